// Round 9
// baseline (287.397 us; speedup 1.0000x reference)
//
#include <hip/hip_runtime.h>
#include <hip/hip_bf16.h>
#include <math.h>

// Problem constants
#define TDIM 4096
#define CDIM 256
#define BDIM 8
#define NTOK (BDIM * TDIM)   // 32768 rows
#define HIDDIM 1024
#define NCHUNK 128
#define CHLEN 32             // 4096 / 128

typedef float f32x4 __attribute__((ext_vector_type(4)));
typedef __bf16 bf16x8 __attribute__((ext_vector_type(8)));
typedef __bf16 bf16x4 __attribute__((ext_vector_type(4)));

// async global->LDS, 16 B/lane, lands at wave-uniform base + lane*16
#define GLDS16(gp, lp) __builtin_amdgcn_global_load_lds( \
    (const __attribute__((address_space(1))) void*)(gp), \
    (__attribute__((address_space(3))) void*)(lp), 16, 0, 0)

// s_waitcnt imm: vmcnt[3:0] in [3:0], vmcnt[5:4] in [15:14], lgkm in [11:8]
#define WAITCNT_VM6  0x0F76
#define WAITCNT_VM4  0x0F74
#define WAITCNT_VM2  0x0F72
#define WAITCNT_VM0  0x0F70
#define WAITCNT_VM20 0x4F74   // vmcnt<=20 (hi=01, lo=0100)

__device__ __forceinline__ float sigm(float v) { return 1.0f / (1.0f + __expf(-v)); }

// ---------------------------------------------------------------------------
// Weight pack: fp32 [K,N] -> bf16 (or fp8) transposed [N,K].
//   WkvrT [768][256] bf16 = [Wk^T; Wv^T; Wr^T]
//   WoT   [256][256] bf16
//   Wkfr  [1280][256] bf16 = [Wkf^T; Wrf^T]
//   Wvf8  [256][1024] fp8 e4m3
// ---------------------------------------------------------------------------
__global__ __launch_bounds__(256) void pack_weights(
    const float* __restrict__ Wk, const float* __restrict__ Wv,
    const float* __restrict__ Wr, const float* __restrict__ Wo,
    const float* __restrict__ Wkf, const float* __restrict__ Wvf,
    const float* __restrict__ Wrf,
    __bf16* __restrict__ WkvrT, __bf16* __restrict__ WoT,
    __bf16* __restrict__ Wkfr, unsigned char* __restrict__ Wvf8) {
  long long j = (long long)blockIdx.x * 256 + threadIdx.x;
  if (j < 196608) {
    int n = (int)(j >> 8), k = (int)(j & 255);
    const float* src = (n < 256) ? Wk : (n < 512 ? Wv : Wr);
    WkvrT[j] = (__bf16)src[k * 256 + (n & 255)];
    return;
  }
  j -= 196608;
  if (j < 65536) { int n = (int)(j >> 8), k = (int)(j & 255);
    WoT[j] = (__bf16)Wo[k * 256 + n]; return; }
  j -= 65536;
  if (j < 327680) { int n = (int)(j >> 8), k = (int)(j & 255);
    Wkfr[j] = (__bf16)(n < 1024 ? Wkf[(long long)k * 1024 + n]
                                : Wrf[k * 256 + (n - 1024)]);
    return; }
  j -= 327680;
  if (j < 65536) {            // Wvf8: 4 bytes per thread
    const long long d = j * 4;
    const int n = (int)(d >> 10), k0 = (int)(d & 1023);
    int w = 0;
    w = __builtin_amdgcn_cvt_pk_fp8_f32(Wvf[(long long)k0 * 256 + n],
                                        Wvf[(long long)(k0 + 1) * 256 + n], w, false);
    w = __builtin_amdgcn_cvt_pk_fp8_f32(Wvf[(long long)(k0 + 2) * 256 + n],
                                        Wvf[(long long)(k0 + 3) * 256 + n], w, true);
    *(int*)&Wvf8[d] = w;
    return;
  }
}

// ---------------------------------------------------------------------------
// LayerNorm over C=256: one wave per row, 4 rows/block, float4 loads.
// ---------------------------------------------------------------------------
__global__ __launch_bounds__(256) void ln_kernel(
    const float* __restrict__ x, const float* __restrict__ gamma,
    const float* __restrict__ beta, __bf16* __restrict__ h) {
  const int wave = threadIdx.x >> 6, lane = threadIdx.x & 63;
  const long long row = (long long)blockIdx.x * 4 + wave;
  const long long base = row * CDIM + lane * 4;
  const f32x4 v = *(const f32x4*)&x[base];
  float s = v[0] + v[1] + v[2] + v[3];
  float s2 = v[0]*v[0] + v[1]*v[1] + v[2]*v[2] + v[3]*v[3];
  #pragma unroll
  for (int o = 1; o < 64; o <<= 1) { s += __shfl_xor(s, o); s2 += __shfl_xor(s2, o); }
  const float mean = s * (1.0f / CDIM);
  const float var = s2 * (1.0f / CDIM) - mean * mean;
  const float rstd = rsqrtf(var + 1e-5f);
  const f32x4 g4 = *(const f32x4*)&gamma[lane * 4];
  const f32x4 b4 = *(const f32x4*)&beta[lane * 4];
  bf16x4 o;
  #pragma unroll
  for (int r = 0; r < 4; r++) o[r] = (__bf16)((v[r] - mean) * rstd * g4[r] + b4[r]);
  *(bf16x4*)&h[base] = o;
}

// ---------------------------------------------------------------------------
// Pipelined bf16 MFMA GEMM, K=256, with MT m-tiles per block sharing ONE
// continuous pipeline (prologue/drain amortized over 8*MT iterations).
// Triple-buffered LDS, PD2, raw s_barrier + partial vmcnt. Epilogue for
// m-tile t fires mid-stream at (g&7)==7; acc rezeroed. Tile-boundary store
// drain avoided via widened vmcnt<=20 for the 2 iters after each epilogue.
// BM=128 per tile, BN in {128,256}; 4 waves as 2(m) x 2(n).
// Accumulator TRANSPOSED (mfma(fb,fa)): lane (quad,mrow) reg r ->
//   row = mtile+mrow, col = ntile + quad*4 + r (4 consecutive cols/lane).
// EPI 0: planar kvr store, plane = blockIdx.y>>1 (0:k 1:v 2:sigmoid->r)
// EPI 1: (BN=256, N=256, MT=1) FUSED residual+LN -> x1h, h2
// EPI 2: y<8: kk8 = fp8(relu(acc)^2) [stride 1024]; y>=8: g2 = sigmoid [256]
// ---------------------------------------------------------------------------
template <int BN, int EPI, int MT>
__global__ __launch_bounds__(256, 3) void gemm3(
    const __bf16* __restrict__ A, const __bf16* __restrict__ Bt,
    int M, int N,
    __bf16* __restrict__ outH, __bf16* __restrict__ outH2,
    unsigned char* __restrict__ outC,
    const float* __restrict__ srcF,
    const float* __restrict__ gammaP, const float* __restrict__ betaP) {
  constexpr int K = 256;
  constexpr int WNT = BN / 32;        // n-tiles per wave
  constexpr int NBC = BN / 64;        // B staging calls per wave per iter
  __shared__ __bf16 sA[3][128 * 32];
  __shared__ __bf16 sB[3][BN * 32];
  __shared__ float redS[2][128], redQ[2][128];   // EPI1 only

  const int tid = threadIdx.x;
  const int wave = tid >> 6, lane = tid & 63;
  const int quad = lane >> 4, mrow = lane & 15;
  const long long bm = (long long)blockIdx.x * (128 * MT);
  const long long bn = (long long)blockIdx.y * BN;
  const int wm = (wave & 1) * 64, wn = (wave >> 1) * (BN / 2);

  const int lrow = lane >> 2;          // 0..15
  const int lk = (lane & 3) * 8;       // 0,8,16,24

  // g encodes (m-tile = g>>3, k-chunk = g&7)
  auto issue = [&](int g) {
    const int buf = g % 3;
    const long long k0 = (long long)(g & 7) * 32;
    const long long ar = bm + (long long)(g >> 3) * 128;
    const int a0 = wave * 32;
    GLDS16(A + (ar + a0 + lrow) * (long long)K + k0 + lk, &sA[buf][a0 * 32]);
    GLDS16(A + (ar + a0 + 16 + lrow) * (long long)K + k0 + lk, &sA[buf][(a0 + 16) * 32]);
    #pragma unroll
    for (int bc = 0; bc < NBC; bc++) {
      const int r0 = wave * (BN / 4) + bc * 16;
      GLDS16(Bt + (bn + r0 + lrow) * (long long)K + k0 + lk, &sB[buf][r0 * 32]);
    }
  };

  f32x4 acc[4][WNT] = {};

  auto compute = [&](int g) {
    const int buf = g % 3;
    bf16x8 fa[4], fb[WNT];
    #pragma unroll
    for (int mt = 0; mt < 4; mt++)
      fa[mt] = *(const bf16x8*)&sA[buf][(wm + mt * 16 + mrow) * 32 + quad * 8];
    #pragma unroll
    for (int nt = 0; nt < WNT; nt++)
      fb[nt] = *(const bf16x8*)&sB[buf][(wn + nt * 16 + mrow) * 32 + quad * 8];
    #pragma unroll
    for (int mt = 0; mt < 4; mt++)
      #pragma unroll
      for (int nt = 0; nt < WNT; nt++)
        acc[mt][nt] = __builtin_amdgcn_mfma_f32_16x16x32_bf16(fb[nt], fa[mt], acc[mt][nt], 0, 0, 0);
  };

  // mid-stream epilogue for EPI 0 / 2 (pure VGPR + stores; no LDS touch)
  auto epilogue = [&](int mti) {
    const long long rb0 = bm + (long long)mti * 128;
    #pragma unroll
    for (int mt = 0; mt < 4; mt++) {
      #pragma unroll
      for (int nt = 0; nt < WNT; nt++) {
        const long long row = rb0 + wm + mt * 16 + mrow;
        const int cloc = wn + nt * 16 + quad * 4;
        const long long colb = bn + cloc;
        const f32x4 a = acc[mt][nt];
        if (EPI == 0) {
          const int plane = blockIdx.y >> 1;   // BN=128: 2 y-blocks per plane
          __bf16* o = outH + (long long)plane * ((long long)M * 256);
          const long long c2 = colb & 255;
          bf16x4 v;
          if (plane == 2) {
            #pragma unroll
            for (int r = 0; r < 4; r++) v[r] = (__bf16)sigm(a[r]);
          } else {
            #pragma unroll
            for (int r = 0; r < 4; r++) v[r] = (__bf16)a[r];
          }
          *(bf16x4*)&o[row * 256 + c2] = v;
        } else if (EPI == 2) {
          if (blockIdx.y < 8) {
            float t0 = a[0] > 0.0f ? a[0] : 0.0f;
            float t1 = a[1] > 0.0f ? a[1] : 0.0f;
            float t2 = a[2] > 0.0f ? a[2] : 0.0f;
            float t3 = a[3] > 0.0f ? a[3] : 0.0f;
            int w = 0;
            w = __builtin_amdgcn_cvt_pk_fp8_f32(t0 * t0, t1 * t1, w, false);
            w = __builtin_amdgcn_cvt_pk_fp8_f32(t2 * t2, t3 * t3, w, true);
            *(int*)&outC[row * 1024 + colb] = w;
          } else {
            bf16x4 v;
            #pragma unroll
            for (int r = 0; r < 4; r++) v[r] = (__bf16)sigm(a[r]);
            *(bf16x4*)&outH2[row * 256 + (colb - 1024)] = v;
          }
        }
        acc[mt][nt] = (f32x4){0.0f, 0.0f, 0.0f, 0.0f};
      }
    }
  };

  constexpr int total = 8 * MT;
  issue(0);
  issue(1);

  #pragma unroll 1
  for (int g = 0; g < total; g++) {
    if (g == total - 1)
      __builtin_amdgcn_s_waitcnt(WAITCNT_VM0);
    else if (MT > 1 && g >= 8 && (g & 7) <= 1)
      __builtin_amdgcn_s_waitcnt(WAITCNT_VM20);  // stores from boundary sit in queue
    else
      __builtin_amdgcn_s_waitcnt(BN == 256 ? WAITCNT_VM6 : WAITCNT_VM4);
    __builtin_amdgcn_s_barrier();
    if (g + 2 < total) issue(g + 2);
    compute(g);
    if (EPI != 1 && (g & 7) == 7) epilogue(g >> 3);
  }

  if (EPI == 1) {
    // ---- fused residual + LayerNorm (BN==256, N==256, MT==1) ----
    float sum[4] = {0, 0, 0, 0}, sq[4] = {0, 0, 0, 0};
    #pragma unroll
    for (int mt = 0; mt < 4; mt++) {
      #pragma unroll
      for (int nt = 0; nt < WNT; nt++) {
        const long long row = bm + wm + mt * 16 + mrow;
        const long long colb = wn + nt * 16 + quad * 4;
        acc[mt][nt] += *(const f32x4*)&srcF[row * 256 + colb];
        #pragma unroll
        for (int r = 0; r < 4; r++) {
          sum[mt] += acc[mt][nt][r];
          sq[mt] += acc[mt][nt][r] * acc[mt][nt][r];
        }
      }
    }
    #pragma unroll
    for (int mt = 0; mt < 4; mt++) {
      sum[mt] += __shfl_xor(sum[mt], 16); sq[mt] += __shfl_xor(sq[mt], 16);
      sum[mt] += __shfl_xor(sum[mt], 32); sq[mt] += __shfl_xor(sq[mt], 32);
    }
    const int wnh = wave >> 1;
    if (quad == 0) {
      #pragma unroll
      for (int mt = 0; mt < 4; mt++) {
        redS[wnh][wm + mt * 16 + mrow] = sum[mt];
        redQ[wnh][wm + mt * 16 + mrow] = sq[mt];
      }
    }
    __syncthreads();
    #pragma unroll
    for (int mt = 0; mt < 4; mt++) {
      const int rb = wm + mt * 16 + mrow;
      const float ts = redS[0][rb] + redS[1][rb];
      const float tq = redQ[0][rb] + redQ[1][rb];
      const float mean = ts * (1.0f / 256.0f);
      const float rstd = rsqrtf(tq * (1.0f / 256.0f) - mean * mean + 1e-5f);
      const long long row = bm + rb;
      #pragma unroll
      for (int nt = 0; nt < WNT; nt++) {
        const long long colb = wn + nt * 16 + quad * 4;
        const f32x4 g4 = *(const f32x4*)&gammaP[colb];
        const f32x4 b4 = *(const f32x4*)&betaP[colb];
        bf16x4 xo, ho;
        #pragma unroll
        for (int r = 0; r < 4; r++) {
          const float t = acc[mt][nt][r];
          xo[r] = (__bf16)t;
          ho[r] = (__bf16)((t - mean) * rstd * g4[r] + b4[r]);
        }
        *(bf16x4*)&outH[row * 256 + colb] = xo;    // x1h
        *(bf16x4*)&outH2[row * 256 + colb] = ho;   // h2
      }
    }
  }
}

// ---------------------------------------------------------------------------
// fp8 MFMA GEMM (K=1024): out[NTOK,256] = x1h + g2 * (kk8 @ Wvf8^T)
// (unchanged from r8) BM=128, BN=128, triple-buffered byte-LDS, PD2.
// ---------------------------------------------------------------------------
__global__ __launch_bounds__(256, 4) void gemm6(
    const unsigned char* __restrict__ A8, const unsigned char* __restrict__ B8,
    float* __restrict__ outF, const __bf16* __restrict__ srcH,
    const __bf16* __restrict__ gate) {
  __shared__ unsigned char sA[3][128 * 32];
  __shared__ unsigned char sB[3][128 * 32];
  const int tid = threadIdx.x;
  const int wave = tid >> 6, lane = tid & 63;
  const int quad = lane >> 4, mrow = lane & 15;
  const long long bm = (long long)blockIdx.x * 128;
  const long long bn = (long long)blockIdx.y * 128;
  const int wm = (wave & 1) * 64, wn = (wave >> 1) * 64;
  const int srow = lane >> 1;                     // 0..31
  const int hs = (lane & 1) ^ ((lane >> 2) & 1);  // swizzled source half

  auto issue = [&](int g) {
    const int buf = g % 3;
    const long long k0 = (long long)g * 32;
    const int a0 = wave * 32;
    GLDS16(A8 + (bm + a0 + srow) * 1024LL + k0 + hs * 16, &sA[buf][a0 * 32]);
    GLDS16(B8 + (bn + a0 + srow) * 1024LL + k0 + hs * 16, &sB[buf][a0 * 32]);
  };

  f32x4 acc[4][4] = {};
  issue(0);
  issue(1);
  const int sw = (mrow >> 1) & 1;   // de-swizzle bit for fragment reads

  auto compute = [&](int i) {
    const int buf = i % 3;
    long long fa[4], fb[4];
    const int off = ((((quad >> 1) ^ sw) << 4) | ((quad & 1) << 3));
    #pragma unroll
    for (int mt = 0; mt < 4; mt++)
      fa[mt] = *(const long long*)&sA[buf][(wm + mt * 16 + mrow) * 32 + off];
    #pragma unroll
    for (int nt = 0; nt < 4; nt++)
      fb[nt] = *(const long long*)&sB[buf][(wn + nt * 16 + mrow) * 32 + off];
    #pragma unroll
    for (int mt = 0; mt < 4; mt++)
      #pragma unroll
      for (int nt = 0; nt < 4; nt++)
        acc[mt][nt] = __builtin_amdgcn_mfma_f32_16x16x32_fp8_fp8(fb[nt], fa[mt], acc[mt][nt], 0, 0, 0);
  };

  #pragma unroll 1
  for (int i = 0; i < 31; i++) {
    __builtin_amdgcn_s_waitcnt(WAITCNT_VM2);
    __builtin_amdgcn_s_barrier();
    if (i + 2 < 32) issue(i + 2);
    compute(i);
  }
  __builtin_amdgcn_s_waitcnt(WAITCNT_VM0);
  __builtin_amdgcn_s_barrier();
  compute(31);

  #pragma unroll
  for (int mt = 0; mt < 4; mt++) {
    #pragma unroll
    for (int nt = 0; nt < 4; nt++) {
      const long long row = bm + wm + mt * 16 + mrow;
      const long long colb = bn + wn + nt * 16 + quad * 4;
      const long long idx = row * 256 + colb;
      const f32x4 a = acc[mt][nt];
      const bf16x4 s4 = *(const bf16x4*)&srcH[idx];
      const bf16x4 g4 = *(const bf16x4*)&gate[idx];
      f32x4 v;
      #pragma unroll
      for (int r = 0; r < 4; r++) v[r] = (float)s4[r] + (float)g4[r] * a[r];
      *(f32x4*)&outF[idx] = v;
    }
  }
}

// ---------------------------------------------------------------------------
// WKV chunked scan on planar k/v/sr arrays (unchanged). Direct fp32
// recurrence; exponents bounded.
// ---------------------------------------------------------------------------
__global__ __launch_bounds__(256) void wkv_phase1(
    const __bf16* __restrict__ ka, const __bf16* __restrict__ va,
    const float* __restrict__ decay,
    float* __restrict__ Sloc, float* __restrict__ Zloc) {
  const int wave = threadIdx.x >> 6, lane = threadIdx.x & 63;
  const int gi = blockIdx.x * 4 + wave;          // 0..1023
  const int b = gi >> 7, chunk = gi & (NCHUNK - 1);
  const int c0 = lane * 4;
  const f32x4 w4 = *(const f32x4*)&decay[c0];
  f32x4 ew;
  #pragma unroll
  for (int r = 0; r < 4; r++) ew[r] = __expf(w4[r] * (1.0f / TDIM));
  f32x4 S = {0,0,0,0}, Z = {0,0,0,0};
  long long base = ((long long)b * TDIM + (long long)chunk * CHLEN) * 256 + c0;
  #pragma unroll 4
  for (int t = 0; t < CHLEN; t++) {
    const bf16x4 k4 = *(const bf16x4*)&ka[base + (long long)t * 256];
    const bf16x4 v4 = *(const bf16x4*)&va[base + (long long)t * 256];
    #pragma unroll
    for (int r = 0; r < 4; r++) {
      const float ek = __expf((float)k4[r]);
      S[r] = ew[r] * S[r] + ek * (float)v4[r];
      Z[r] = ew[r] * Z[r] + ek;
    }
  }
  const long long o = (long long)gi * 256 + c0;
  *(f32x4*)&Sloc[o] = S;
  *(f32x4*)&Zloc[o] = Z;
}

__global__ __launch_bounds__(256) void wkv_phase2(
    const float* __restrict__ Sloc, const float* __restrict__ Zloc,
    const float* __restrict__ decay,
    float* __restrict__ Sstart, float* __restrict__ Zstart) {
  const int idx = blockIdx.x * 256 + threadIdx.x;  // 0..2047
  const int c = idx & 255;
  const int b = idx >> 8;
  const float w = decay[c] * (1.0f / TDIM);
  const float ewL = __expf(w * (float)CHLEN);
  float S = 0.0f, Z = 0.0f;
  for (int j = 0; j < NCHUNK; j++) {
    const long long o = ((long long)b * NCHUNK + j) * 256 + c;
    Sstart[o] = S;
    Zstart[o] = Z;
    S = ewL * S + Sloc[o];
    Z = ewL * Z + Zloc[o];
  }
}

__global__ __launch_bounds__(256) void wkv_phase3(
    const __bf16* __restrict__ ka, const __bf16* __restrict__ va,
    const __bf16* __restrict__ ra,   // holds sigmoid(r)
    const float* __restrict__ decay, const float* __restrict__ first,
    const float* __restrict__ Sstart, const float* __restrict__ Zstart,
    __bf16* __restrict__ a2) {
  const int wave = threadIdx.x >> 6, lane = threadIdx.x & 63;
  const int gi = blockIdx.x * 4 + wave;
  const int b = gi >> 7, chunk = gi & (NCHUNK - 1);
  const int c0 = lane * 4;
  const f32x4 w4 = *(const f32x4*)&decay[c0];
  const f32x4 u4 = *(const f32x4*)&first[c0];
  f32x4 ew, eu;
  #pragma unroll
  for (int r = 0; r < 4; r++) {
    ew[r] = __expf(w4[r] * (1.0f / TDIM));
    eu[r] = __expf(u4[r] * (1.0f / TDIM));
  }
  const long long so = (long long)gi * 256 + c0;
  f32x4 S = *(const f32x4*)&Sstart[so];
  f32x4 Z = *(const f32x4*)&Zstart[so];
  long long base = ((long long)b * TDIM + (long long)chunk * CHLEN) * 256 + c0;
  #pragma unroll 2
  for (int t = 0; t < CHLEN; t++) {
    const long long p = base + (long long)t * 256;
    const bf16x4 k4 = *(const bf16x4*)&ka[p];
    const bf16x4 v4 = *(const bf16x4*)&va[p];
    const bf16x4 r4 = *(const bf16x4*)&ra[p];
    bf16x4 o;
    #pragma unroll
    for (int r = 0; r < 4; r++) {
      const float ek = __expf((float)k4[r]);
      const float E = eu[r] * ek;
      const float y = (S[r] + E * (float)v4[r]) / (Z[r] + E);
      o[r] = (__bf16)((float)r4[r] * y);
      S[r] = ew[r] * S[r] + ek * (float)v4[r];
      Z[r] = ew[r] * Z[r] + ek;
    }
    *(bf16x4*)&a2[p] = o;
  }
}

// ---------------------------------------------------------------------------
// Workspace layout (peak ~162 MB):
//   [0)    ka 16M | [16M) va | [32M) ra (=sigmoid r)
//   [48M)  a2 16M -> reused as g2buf after EPI1
//   [64M)  h 16M  -> reused as h2 (written by fused EPI1)
//   [80M)  x1h 16M
//   [96M)  scan state S/Z 4M (dead before kk8) then kk8 (fp8 33.5M)
//   [160M) packed weights (~1.5 MB)
// ---------------------------------------------------------------------------
extern "C" void kernel_launch(void* const* d_in, const int* in_sizes, int n_in,
                              void* d_out, int out_size, void* d_ws, size_t ws_size,
                              hipStream_t stream) {
  const float* x     = (const float*)d_in[0];
  const float* Wk    = (const float*)d_in[1];
  const float* Wv    = (const float*)d_in[2];
  const float* Wr    = (const float*)d_in[3];
  const float* Wo    = (const float*)d_in[4];
  const float* Wkf   = (const float*)d_in[5];
  const float* Wvf   = (const float*)d_in[6];
  const float* Wrf   = (const float*)d_in[7];
  const float* g1    = (const float*)d_in[8];
  const float* b1    = (const float*)d_in[9];
  const float* g2    = (const float*)d_in[10];
  const float* b2    = (const float*)d_in[11];
  const float* decay = (const float*)d_in[12];
  const float* first = (const float*)d_in[13];
  float* out = (float*)d_out;
  char* ws = (char*)d_ws;

  __bf16* ka     = (__bf16*)(ws + 0);
  __bf16* va     = (__bf16*)(ws + 16777216LL);
  __bf16* ra     = (__bf16*)(ws + 33554432LL);
  __bf16* a2     = (__bf16*)(ws + 50331648LL);
  __bf16* g2buf  = (__bf16*)(ws + 50331648LL);      // reuses a2 (dead after EPI1)
  __bf16* hbuf   = (__bf16*)(ws + 67108864LL);
  __bf16* h2     = (__bf16*)(ws + 67108864LL);      // reuses hbuf (dead after EPI0)
  __bf16* x1h    = (__bf16*)(ws + 83886080LL);
  float*  Sloc   = (float*)(ws + 100663296LL);      // dead before kk8 written
  float*  Zloc   = (float*)(ws + 101711872LL);
  float*  Sstart = (float*)(ws + 102760448LL);
  float*  Zstart = (float*)(ws + 103809024LL);
  unsigned char* kk8 = (unsigned char*)(ws + 100663296LL);   // overwrites scan state
  __bf16* WkvrT  = (__bf16*)(ws + 167772160LL);
  __bf16* WoT    = (__bf16*)(ws + 168165376LL);
  __bf16* Wkfr   = (__bf16*)(ws + 168296448LL);
  unsigned char* Wvf8 = (unsigned char*)(ws + 168951808LL);

  pack_weights<<<2560, 256, 0, stream>>>(Wk, Wv, Wr, Wo, Wkf, Wvf, Wrf,
                                         WkvrT, WoT, Wkfr, Wvf8);

  // --- SpatialMix ---
  ln_kernel<<<NTOK / 4, 256, 0, stream>>>(x, g1, b1, hbuf);
  gemm3<128, 0, 2><<<dim3(NTOK / 256, 6), 256, 0, stream>>>(
      hbuf, WkvrT, NTOK, 768, ka, nullptr, nullptr, nullptr, nullptr, nullptr);
  wkv_phase1<<<BDIM * NCHUNK / 4, 256, 0, stream>>>(ka, va, decay, Sloc, Zloc);
  wkv_phase2<<<BDIM, 256, 0, stream>>>(Sloc, Zloc, decay, Sstart, Zstart);
  wkv_phase3<<<BDIM * NCHUNK / 4, 256, 0, stream>>>(ka, va, ra, decay, first,
                                                    Sstart, Zstart, a2);
  // x1 = x + a2@Wo, fused with LN2: writes x1h (bf16) and h2 = LN(x1)
  gemm3<256, 1, 1><<<dim3(NTOK / 128, 1), 256, 0, stream>>>(
      a2, WoT, NTOK, 256, x1h, h2, nullptr, x, g2, b2);

  // --- ChannelMix ---
  gemm3<128, 2, 4><<<dim3(NTOK / 512, 10), 256, 0, stream>>>(
      h2, Wkfr, NTOK, 1280, nullptr, g2buf, kk8, nullptr, nullptr, nullptr);
  gemm6<<<dim3(NTOK / 128, 2), 256, 0, stream>>>(
      kk8, Wvf8, out, x1h, g2buf);
}

// Round 11
// 279.074 us; speedup vs baseline: 1.0298x; 1.0298x over previous
//
#include <hip/hip_runtime.h>
#include <hip/hip_bf16.h>
#include <math.h>

// Problem constants
#define TDIM 4096
#define CDIM 256
#define BDIM 8
#define NTOK (BDIM * TDIM)   // 32768 rows
#define HIDDIM 1024
#define NCHUNK 256
#define CHLEN 16             // 4096 / 256

typedef float f32x4 __attribute__((ext_vector_type(4)));
typedef __bf16 bf16x8 __attribute__((ext_vector_type(8)));
typedef __bf16 bf16x4 __attribute__((ext_vector_type(4)));

// async global->LDS, 16 B/lane, lands at wave-uniform base + lane*16
#define GLDS16(gp, lp) __builtin_amdgcn_global_load_lds( \
    (const __attribute__((address_space(1))) void*)(gp), \
    (__attribute__((address_space(3))) void*)(lp), 16, 0, 0)

// s_waitcnt imm: vmcnt[3:0] in [3:0], vmcnt[5:4] in [15:14], lgkm in [11:8]
#define WAITCNT_VM6  0x0F76
#define WAITCNT_VM5  0x0F75
#define WAITCNT_VM4  0x0F74
#define WAITCNT_VM2  0x0F72
#define WAITCNT_VM0  0x0F70
#define WAITCNT_VM20 0x4F74   // vmcnt<=20 (hi=01, lo=0100)

__device__ __forceinline__ float sigm(float v) { return 1.0f / (1.0f + __expf(-v)); }

// ---------------------------------------------------------------------------
// Weight pack: fp32 [K,N] -> bf16 (or fp8) transposed [N,K].
// ---------------------------------------------------------------------------
__global__ __launch_bounds__(256) void pack_weights(
    const float* __restrict__ Wk, const float* __restrict__ Wv,
    const float* __restrict__ Wr, const float* __restrict__ Wo,
    const float* __restrict__ Wkf, const float* __restrict__ Wvf,
    const float* __restrict__ Wrf,
    __bf16* __restrict__ WkvrT, __bf16* __restrict__ WoT,
    __bf16* __restrict__ Wkfr, unsigned char* __restrict__ Wvf8) {
  long long j = (long long)blockIdx.x * 256 + threadIdx.x;
  if (j < 196608) {
    int n = (int)(j >> 8), k = (int)(j & 255);
    const float* src = (n < 256) ? Wk : (n < 512 ? Wv : Wr);
    WkvrT[j] = (__bf16)src[k * 256 + (n & 255)];
    return;
  }
  j -= 196608;
  if (j < 65536) { int n = (int)(j >> 8), k = (int)(j & 255);
    WoT[j] = (__bf16)Wo[k * 256 + n]; return; }
  j -= 65536;
  if (j < 327680) { int n = (int)(j >> 8), k = (int)(j & 255);
    Wkfr[j] = (__bf16)(n < 1024 ? Wkf[(long long)k * 1024 + n]
                                : Wrf[k * 256 + (n - 1024)]);
    return; }
  j -= 327680;
  if (j < 65536) {            // Wvf8: 4 bytes per thread
    const long long d = j * 4;
    const int n = (int)(d >> 10), k0 = (int)(d & 1023);
    int w = 0;
    w = __builtin_amdgcn_cvt_pk_fp8_f32(Wvf[(long long)k0 * 256 + n],
                                        Wvf[(long long)(k0 + 1) * 256 + n], w, false);
    w = __builtin_amdgcn_cvt_pk_fp8_f32(Wvf[(long long)(k0 + 2) * 256 + n],
                                        Wvf[(long long)(k0 + 3) * 256 + n], w, true);
    *(int*)&Wvf8[d] = w;
    return;
  }
}

// ---------------------------------------------------------------------------
// LayerNorm over C=256: one wave per row, 4 rows/block, float4 loads.
// ---------------------------------------------------------------------------
__global__ __launch_bounds__(256) void ln_kernel(
    const float* __restrict__ x, const float* __restrict__ gamma,
    const float* __restrict__ beta, __bf16* __restrict__ h) {
  const int wave = threadIdx.x >> 6, lane = threadIdx.x & 63;
  const long long row = (long long)blockIdx.x * 4 + wave;
  const long long base = row * CDIM + lane * 4;
  const f32x4 v = *(const f32x4*)&x[base];
  float s = v[0] + v[1] + v[2] + v[3];
  float s2 = v[0]*v[0] + v[1]*v[1] + v[2]*v[2] + v[3]*v[3];
  #pragma unroll
  for (int o = 1; o < 64; o <<= 1) { s += __shfl_xor(s, o); s2 += __shfl_xor(s2, o); }
  const float mean = s * (1.0f / CDIM);
  const float var = s2 * (1.0f / CDIM) - mean * mean;
  const float rstd = rsqrtf(var + 1e-5f);
  const f32x4 g4 = *(const f32x4*)&gamma[lane * 4];
  const f32x4 b4 = *(const f32x4*)&beta[lane * 4];
  bf16x4 o;
  #pragma unroll
  for (int r = 0; r < 4; r++) o[r] = (__bf16)((v[r] - mean) * rstd * g4[r] + b4[r]);
  *(bf16x4*)&h[base] = o;
}

// ---------------------------------------------------------------------------
// Pipelined bf16 MFMA GEMM, K=256, MT m-tiles per block in ONE continuous
// pipeline (triple-buffered LDS, PD2, raw s_barrier + partial vmcnt).
// Mid-stream epilogue at (g&7)==7; boundary iters use widened vmcnt<=20.
// BM=128/tile, BN=128; 4 waves as 2(m) x 2(n).
// Accumulator TRANSPOSED: lane (quad,mrow) reg r -> row=mtile+mrow,
// col=ntile+quad*4+r.
// EPI 0: planar kvr store, plane = blockIdx.y>>1 (0:k 1:v 2:sigmoid->r)
// EPI 2: y<8: kk8 = fp8(relu(acc)^2) [stride 1024]; y>=8: g2 = sigmoid [256]
// ---------------------------------------------------------------------------
template <int BN, int EPI, int MT>
__global__ __launch_bounds__(256, 3) void gemm3(
    const __bf16* __restrict__ A, const __bf16* __restrict__ Bt,
    int M, int N,
    __bf16* __restrict__ outH, __bf16* __restrict__ outH2,
    unsigned char* __restrict__ outC) {
  constexpr int K = 256;
  constexpr int WNT = BN / 32;
  constexpr int NBC = BN / 64;
  __shared__ __bf16 sA[3][128 * 32];
  __shared__ __bf16 sB[3][BN * 32];

  const int tid = threadIdx.x;
  const int wave = tid >> 6, lane = tid & 63;
  const int quad = lane >> 4, mrow = lane & 15;
  const long long bm = (long long)blockIdx.x * (128 * MT);
  const long long bn = (long long)blockIdx.y * BN;
  const int wm = (wave & 1) * 64, wn = (wave >> 1) * (BN / 2);

  const int lrow = lane >> 2;
  const int lk = (lane & 3) * 8;

  auto issue = [&](int g) {
    const int buf = g % 3;
    const long long k0 = (long long)(g & 7) * 32;
    const long long ar = bm + (long long)(g >> 3) * 128;
    const int a0 = wave * 32;
    GLDS16(A + (ar + a0 + lrow) * (long long)K + k0 + lk, &sA[buf][a0 * 32]);
    GLDS16(A + (ar + a0 + 16 + lrow) * (long long)K + k0 + lk, &sA[buf][(a0 + 16) * 32]);
    #pragma unroll
    for (int bc = 0; bc < NBC; bc++) {
      const int r0 = wave * (BN / 4) + bc * 16;
      GLDS16(Bt + (bn + r0 + lrow) * (long long)K + k0 + lk, &sB[buf][r0 * 32]);
    }
  };

  f32x4 acc[4][WNT] = {};

  auto compute = [&](int g) {
    const int buf = g % 3;
    bf16x8 fa[4], fb[WNT];
    #pragma unroll
    for (int mt = 0; mt < 4; mt++)
      fa[mt] = *(const bf16x8*)&sA[buf][(wm + mt * 16 + mrow) * 32 + quad * 8];
    #pragma unroll
    for (int nt = 0; nt < WNT; nt++)
      fb[nt] = *(const bf16x8*)&sB[buf][(wn + nt * 16 + mrow) * 32 + quad * 8];
    #pragma unroll
    for (int mt = 0; mt < 4; mt++)
      #pragma unroll
      for (int nt = 0; nt < WNT; nt++)
        acc[mt][nt] = __builtin_amdgcn_mfma_f32_16x16x32_bf16(fb[nt], fa[mt], acc[mt][nt], 0, 0, 0);
  };

  auto epilogue = [&](int mti) {
    const long long rb0 = bm + (long long)mti * 128;
    #pragma unroll
    for (int mt = 0; mt < 4; mt++) {
      #pragma unroll
      for (int nt = 0; nt < WNT; nt++) {
        const long long row = rb0 + wm + mt * 16 + mrow;
        const int cloc = wn + nt * 16 + quad * 4;
        const long long colb = bn + cloc;
        const f32x4 a = acc[mt][nt];
        if (EPI == 0) {
          const int plane = blockIdx.y >> 1;
          __bf16* o = outH + (long long)plane * ((long long)M * 256);
          const long long c2 = colb & 255;
          bf16x4 v;
          if (plane == 2) {
            #pragma unroll
            for (int r = 0; r < 4; r++) v[r] = (__bf16)sigm(a[r]);
          } else {
            #pragma unroll
            for (int r = 0; r < 4; r++) v[r] = (__bf16)a[r];
          }
          *(bf16x4*)&o[row * 256 + c2] = v;
        } else if (EPI == 2) {
          if (blockIdx.y < 8) {
            float t0 = a[0] > 0.0f ? a[0] : 0.0f;
            float t1 = a[1] > 0.0f ? a[1] : 0.0f;
            float t2 = a[2] > 0.0f ? a[2] : 0.0f;
            float t3 = a[3] > 0.0f ? a[3] : 0.0f;
            int w = 0;
            w = __builtin_amdgcn_cvt_pk_fp8_f32(t0 * t0, t1 * t1, w, false);
            w = __builtin_amdgcn_cvt_pk_fp8_f32(t2 * t2, t3 * t3, w, true);
            *(int*)&outC[row * 1024 + colb] = w;
          } else {
            bf16x4 v;
            #pragma unroll
            for (int r = 0; r < 4; r++) v[r] = (__bf16)sigm(a[r]);
            *(bf16x4*)&outH2[row * 256 + (colb - 1024)] = v;
          }
        }
        acc[mt][nt] = (f32x4){0.0f, 0.0f, 0.0f, 0.0f};
      }
    }
  };

  constexpr int total = 8 * MT;
  issue(0);
  issue(1);

  #pragma unroll 1
  for (int g = 0; g < total; g++) {
    if (g == total - 1) {
      __builtin_amdgcn_s_waitcnt(WAITCNT_VM0);
    } else if (MT > 1 && g >= 8 && (g & 7) <= 1) {
      __builtin_amdgcn_s_waitcnt(WAITCNT_VM20);
    } else if (BN == 256) {
      __builtin_amdgcn_s_waitcnt(WAITCNT_VM6);
    } else {
      __builtin_amdgcn_s_waitcnt(WAITCNT_VM4);
    }
    __builtin_amdgcn_s_barrier();
    if (g + 2 < total) issue(g + 2);
    compute(g);
    if ((g & 7) == 7) epilogue(g >> 3);
  }
}

// ---------------------------------------------------------------------------
// Fused x1 = x + a2@WoT, LN2 -> h2, both bf16. BM=64 (grid 512 = 2/CU),
// BN = full 256; 4 waves each own 64 cols of all 64 rows (acc 4x4).
// Same triple-buffer PD2 pipeline (5 GLDS16/thread/iter -> wait vmcnt<=5).
// LN: per-lane partials -> quad shuffle -> 4-wave LDS reduction.
// ---------------------------------------------------------------------------
__global__ __launch_bounds__(256, 2) void gemm7(
    const __bf16* __restrict__ A, const __bf16* __restrict__ Bt,
    const float* __restrict__ x,
    const float* __restrict__ gammaP, const float* __restrict__ betaP,
    __bf16* __restrict__ x1h, __bf16* __restrict__ h2) {
  constexpr int K = 256;
  __shared__ __bf16 sA[3][64 * 32];
  __shared__ __bf16 sB[3][256 * 32];
  __shared__ float redS[4][64], redQ[4][64];

  const int tid = threadIdx.x;
  const int wave = tid >> 6, lane = tid & 63;
  const int quad = lane >> 4, mrow = lane & 15;
  const long long bm = (long long)blockIdx.x * 64;
  const int wn = wave * 64;
  const int lrow = lane >> 2;
  const int lk = (lane & 3) * 8;

  auto issue = [&](int g) {
    const int buf = g % 3;
    const long long k0 = (long long)g * 32;
    GLDS16(A + (bm + wave * 16 + lrow) * (long long)K + k0 + lk,
           &sA[buf][(wave * 16) * 32]);
    #pragma unroll
    for (int bc = 0; bc < 4; bc++) {
      const int r0 = wave * 64 + bc * 16;
      GLDS16(Bt + (r0 + lrow) * (long long)K + k0 + lk, &sB[buf][r0 * 32]);
    }
  };

  f32x4 acc[4][4] = {};

  auto compute = [&](int g) {
    const int buf = g % 3;
    bf16x8 fa[4], fb[4];
    #pragma unroll
    for (int mt = 0; mt < 4; mt++)
      fa[mt] = *(const bf16x8*)&sA[buf][(mt * 16 + mrow) * 32 + quad * 8];
    #pragma unroll
    for (int nt = 0; nt < 4; nt++)
      fb[nt] = *(const bf16x8*)&sB[buf][(wn + nt * 16 + mrow) * 32 + quad * 8];
    #pragma unroll
    for (int mt = 0; mt < 4; mt++)
      #pragma unroll
      for (int nt = 0; nt < 4; nt++)
        acc[mt][nt] = __builtin_amdgcn_mfma_f32_16x16x32_bf16(fb[nt], fa[mt], acc[mt][nt], 0, 0, 0);
  };

  issue(0);
  issue(1);
  #pragma unroll 1
  for (int g = 0; g < 8; g++) {
    if (g == 7) {
      __builtin_amdgcn_s_waitcnt(WAITCNT_VM0);
    } else {
      __builtin_amdgcn_s_waitcnt(WAITCNT_VM5);
    }
    __builtin_amdgcn_s_barrier();
    if (g + 2 < 8) issue(g + 2);
    compute(g);
  }

  // residual add + LN partials
  float sum[4] = {0, 0, 0, 0}, sq[4] = {0, 0, 0, 0};
  #pragma unroll
  for (int mt = 0; mt < 4; mt++) {
    #pragma unroll
    for (int nt = 0; nt < 4; nt++) {
      const long long row = bm + mt * 16 + mrow;
      const long long colb = wn + nt * 16 + quad * 4;
      acc[mt][nt] += *(const f32x4*)&x[row * 256 + colb];
      #pragma unroll
      for (int r = 0; r < 4; r++) {
        sum[mt] += acc[mt][nt][r];
        sq[mt] += acc[mt][nt][r] * acc[mt][nt][r];
      }
    }
  }
  #pragma unroll
  for (int mt = 0; mt < 4; mt++) {   // reduce over quad (lane bits 4,5)
    sum[mt] += __shfl_xor(sum[mt], 16); sq[mt] += __shfl_xor(sq[mt], 16);
    sum[mt] += __shfl_xor(sum[mt], 32); sq[mt] += __shfl_xor(sq[mt], 32);
  }
  if (quad == 0) {
    #pragma unroll
    for (int mt = 0; mt < 4; mt++) {
      redS[wave][mt * 16 + mrow] = sum[mt];
      redQ[wave][mt * 16 + mrow] = sq[mt];
    }
  }
  __syncthreads();
  #pragma unroll
  for (int mt = 0; mt < 4; mt++) {
    const int rb = mt * 16 + mrow;
    const float ts = redS[0][rb] + redS[1][rb] + redS[2][rb] + redS[3][rb];
    const float tq = redQ[0][rb] + redQ[1][rb] + redQ[2][rb] + redQ[3][rb];
    const float mean = ts * (1.0f / 256.0f);
    const float rstd = rsqrtf(tq * (1.0f / 256.0f) - mean * mean + 1e-5f);
    const long long row = bm + rb;
    #pragma unroll
    for (int nt = 0; nt < 4; nt++) {
      const long long colb = wn + nt * 16 + quad * 4;
      const f32x4 g4 = *(const f32x4*)&gammaP[colb];
      const f32x4 b4 = *(const f32x4*)&betaP[colb];
      bf16x4 xo, ho;
      #pragma unroll
      for (int r = 0; r < 4; r++) {
        const float t = acc[mt][nt][r];
        xo[r] = (__bf16)t;
        ho[r] = (__bf16)((t - mean) * rstd * g4[r] + b4[r]);
      }
      *(bf16x4*)&x1h[row * 256 + colb] = xo;
      *(bf16x4*)&h2[row * 256 + colb] = ho;
    }
  }
}

// ---------------------------------------------------------------------------
// fp8 MFMA GEMM (K=1024): out[NTOK,256] = x1h + g2 * (kk8 @ Wvf8^T)
// (unchanged) BM=128, BN=128, triple-buffered byte-LDS, PD2.
// ---------------------------------------------------------------------------
__global__ __launch_bounds__(256, 4) void gemm6(
    const unsigned char* __restrict__ A8, const unsigned char* __restrict__ B8,
    float* __restrict__ outF, const __bf16* __restrict__ srcH,
    const __bf16* __restrict__ gate) {
  __shared__ unsigned char sA[3][128 * 32];
  __shared__ unsigned char sB[3][128 * 32];
  const int tid = threadIdx.x;
  const int wave = tid >> 6, lane = tid & 63;
  const int quad = lane >> 4, mrow = lane & 15;
  const long long bm = (long long)blockIdx.x * 128;
  const long long bn = (long long)blockIdx.y * 128;
  const int wm = (wave & 1) * 64, wn = (wave >> 1) * 64;
  const int srow = lane >> 1;
  const int hs = (lane & 1) ^ ((lane >> 2) & 1);

  auto issue = [&](int g) {
    const int buf = g % 3;
    const long long k0 = (long long)g * 32;
    const int a0 = wave * 32;
    GLDS16(A8 + (bm + a0 + srow) * 1024LL + k0 + hs * 16, &sA[buf][a0 * 32]);
    GLDS16(B8 + (bn + a0 + srow) * 1024LL + k0 + hs * 16, &sB[buf][a0 * 32]);
  };

  f32x4 acc[4][4] = {};
  issue(0);
  issue(1);
  const int sw = (mrow >> 1) & 1;

  auto compute = [&](int i) {
    const int buf = i % 3;
    long long fa[4], fb[4];
    const int off = ((((quad >> 1) ^ sw) << 4) | ((quad & 1) << 3));
    #pragma unroll
    for (int mt = 0; mt < 4; mt++)
      fa[mt] = *(const long long*)&sA[buf][(wm + mt * 16 + mrow) * 32 + off];
    #pragma unroll
    for (int nt = 0; nt < 4; nt++)
      fb[nt] = *(const long long*)&sB[buf][(wn + nt * 16 + mrow) * 32 + off];
    #pragma unroll
    for (int mt = 0; mt < 4; mt++)
      #pragma unroll
      for (int nt = 0; nt < 4; nt++)
        acc[mt][nt] = __builtin_amdgcn_mfma_f32_16x16x32_fp8_fp8(fb[nt], fa[mt], acc[mt][nt], 0, 0, 0);
  };

  #pragma unroll 1
  for (int i = 0; i < 31; i++) {
    __builtin_amdgcn_s_waitcnt(WAITCNT_VM2);
    __builtin_amdgcn_s_barrier();
    if (i + 2 < 32) issue(i + 2);
    compute(i);
  }
  __builtin_amdgcn_s_waitcnt(WAITCNT_VM0);
  __builtin_amdgcn_s_barrier();
  compute(31);

  #pragma unroll
  for (int mt = 0; mt < 4; mt++) {
    #pragma unroll
    for (int nt = 0; nt < 4; nt++) {
      const long long row = bm + wm + mt * 16 + mrow;
      const long long colb = bn + wn + nt * 16 + quad * 4;
      const long long idx = row * 256 + colb;
      const f32x4 a = acc[mt][nt];
      const bf16x4 s4 = *(const bf16x4*)&srcH[idx];
      const bf16x4 g4 = *(const bf16x4*)&gate[idx];
      f32x4 v;
      #pragma unroll
      for (int r = 0; r < 4; r++) v[r] = (float)s4[r] + (float)g4[r] * a[r];
      *(f32x4*)&outF[idx] = v;
    }
  }
}

// ---------------------------------------------------------------------------
// WKV chunked scan on planar k/v/sr arrays. NCHUNK=256 (CHLEN=16) -> 512
// blocks = 2/CU for latency hiding. Direct fp32 recurrence.
// ---------------------------------------------------------------------------
__global__ __launch_bounds__(256) void wkv_phase1(
    const __bf16* __restrict__ ka, const __bf16* __restrict__ va,
    const float* __restrict__ decay,
    float* __restrict__ Sloc, float* __restrict__ Zloc) {
  const int wave = threadIdx.x >> 6, lane = threadIdx.x & 63;
  const int gi = blockIdx.x * 4 + wave;          // 0..2047
  const int b = gi >> 8, chunk = gi & (NCHUNK - 1);
  const int c0 = lane * 4;
  const f32x4 w4 = *(const f32x4*)&decay[c0];
  f32x4 ew;
  #pragma unroll
  for (int r = 0; r < 4; r++) ew[r] = __expf(w4[r] * (1.0f / TDIM));
  f32x4 S = {0,0,0,0}, Z = {0,0,0,0};
  long long base = ((long long)b * TDIM + (long long)chunk * CHLEN) * 256 + c0;
  #pragma unroll 4
  for (int t = 0; t < CHLEN; t++) {
    const bf16x4 k4 = *(const bf16x4*)&ka[base + (long long)t * 256];
    const bf16x4 v4 = *(const bf16x4*)&va[base + (long long)t * 256];
    #pragma unroll
    for (int r = 0; r < 4; r++) {
      const float ek = __expf((float)k4[r]);
      S[r] = ew[r] * S[r] + ek * (float)v4[r];
      Z[r] = ew[r] * Z[r] + ek;
    }
  }
  const long long o = (long long)gi * 256 + c0;
  *(f32x4*)&Sloc[o] = S;
  *(f32x4*)&Zloc[o] = Z;
}

__global__ __launch_bounds__(256) void wkv_phase2(
    const float* __restrict__ Sloc, const float* __restrict__ Zloc,
    const float* __restrict__ decay,
    float* __restrict__ Sstart, float* __restrict__ Zstart) {
  const int idx = blockIdx.x * 256 + threadIdx.x;  // 0..2047
  const int c = idx & 255;
  const int b = idx >> 8;
  const float w = decay[c] * (1.0f / TDIM);
  const float ewL = __expf(w * (float)CHLEN);
  float S = 0.0f, Z = 0.0f;
  for (int j = 0; j < NCHUNK; j++) {
    const long long o = ((long long)b * NCHUNK + j) * 256 + c;
    Sstart[o] = S;
    Zstart[o] = Z;
    S = ewL * S + Sloc[o];
    Z = ewL * Z + Zloc[o];
  }
}

__global__ __launch_bounds__(256) void wkv_phase3(
    const __bf16* __restrict__ ka, const __bf16* __restrict__ va,
    const __bf16* __restrict__ ra,   // holds sigmoid(r)
    const float* __restrict__ decay, const float* __restrict__ first,
    const float* __restrict__ Sstart, const float* __restrict__ Zstart,
    __bf16* __restrict__ a2) {
  const int wave = threadIdx.x >> 6, lane = threadIdx.x & 63;
  const int gi = blockIdx.x * 4 + wave;
  const int b = gi >> 8, chunk = gi & (NCHUNK - 1);
  const int c0 = lane * 4;
  const f32x4 w4 = *(const f32x4*)&decay[c0];
  const f32x4 u4 = *(const f32x4*)&first[c0];
  f32x4 ew, eu;
  #pragma unroll
  for (int r = 0; r < 4; r++) {
    ew[r] = __expf(w4[r] * (1.0f / TDIM));
    eu[r] = __expf(u4[r] * (1.0f / TDIM));
  }
  const long long so = (long long)gi * 256 + c0;
  f32x4 S = *(const f32x4*)&Sstart[so];
  f32x4 Z = *(const f32x4*)&Zstart[so];
  long long base = ((long long)b * TDIM + (long long)chunk * CHLEN) * 256 + c0;
  #pragma unroll 2
  for (int t = 0; t < CHLEN; t++) {
    const long long p = base + (long long)t * 256;
    const bf16x4 k4 = *(const bf16x4*)&ka[p];
    const bf16x4 v4 = *(const bf16x4*)&va[p];
    const bf16x4 r4 = *(const bf16x4*)&ra[p];
    bf16x4 o;
    #pragma unroll
    for (int r = 0; r < 4; r++) {
      const float ek = __expf((float)k4[r]);
      const float E = eu[r] * ek;
      const float y = (S[r] + E * (float)v4[r]) / (Z[r] + E);
      o[r] = (__bf16)((float)r4[r] * y);
      S[r] = ew[r] * S[r] + ek * (float)v4[r];
      Z[r] = ew[r] * Z[r] + ek;
    }
    *(bf16x4*)&a2[p] = o;
  }
}

// ---------------------------------------------------------------------------
// Workspace layout (peak ~170 MB):
//   [0)    ka 16M | [16M) va | [32M) ra (=sigmoid r)
//   [48M)  a2 16M -> reused as g2buf after gemm7
//   [64M)  h 16M  -> reused as h2 (written by gemm7)
//   [80M)  x1h 16M
//   [96M)  kk8 (fp8, 32M)
//   [128M) scan state S/Z (4 x 2M, no aliasing)
//   [160M) packed weights (~1.5 MB)
// ---------------------------------------------------------------------------
extern "C" void kernel_launch(void* const* d_in, const int* in_sizes, int n_in,
                              void* d_out, int out_size, void* d_ws, size_t ws_size,
                              hipStream_t stream) {
  const float* x     = (const float*)d_in[0];
  const float* Wk    = (const float*)d_in[1];
  const float* Wv    = (const float*)d_in[2];
  const float* Wr    = (const float*)d_in[3];
  const float* Wo    = (const float*)d_in[4];
  const float* Wkf   = (const float*)d_in[5];
  const float* Wvf   = (const float*)d_in[6];
  const float* Wrf   = (const float*)d_in[7];
  const float* g1    = (const float*)d_in[8];
  const float* b1    = (const float*)d_in[9];
  const float* g2    = (const float*)d_in[10];
  const float* b2    = (const float*)d_in[11];
  const float* decay = (const float*)d_in[12];
  const float* first = (const float*)d_in[13];
  float* out = (float*)d_out;
  char* ws = (char*)d_ws;

  __bf16* ka     = (__bf16*)(ws + 0);
  __bf16* va     = (__bf16*)(ws + 16777216LL);
  __bf16* ra     = (__bf16*)(ws + 33554432LL);
  __bf16* a2     = (__bf16*)(ws + 50331648LL);
  __bf16* g2buf  = (__bf16*)(ws + 50331648LL);      // reuses a2 (dead after gemm7)
  __bf16* hbuf   = (__bf16*)(ws + 67108864LL);
  __bf16* h2     = (__bf16*)(ws + 67108864LL);      // reuses hbuf (dead after EPI0)
  __bf16* x1h    = (__bf16*)(ws + 83886080LL);
  unsigned char* kk8 = (unsigned char*)(ws + 100663296LL);
  float*  Sloc   = (float*)(ws + 134217728LL);
  float*  Zloc   = (float*)(ws + 137363456LL);
  float*  Sstart = (float*)(ws + 140509184LL);
  float*  Zstart = (float*)(ws + 143654912LL);
  __bf16* WkvrT  = (__bf16*)(ws + 167772160LL);
  __bf16* WoT    = (__bf16*)(ws + 168165376LL);
  __bf16* Wkfr   = (__bf16*)(ws + 168296448LL);
  unsigned char* Wvf8 = (unsigned char*)(ws + 168951808LL);

  pack_weights<<<2560, 256, 0, stream>>>(Wk, Wv, Wr, Wo, Wkf, Wvf, Wrf,
                                         WkvrT, WoT, Wkfr, Wvf8);

  // --- SpatialMix ---
  ln_kernel<<<NTOK / 4, 256, 0, stream>>>(x, g1, b1, hbuf);
  gemm3<128, 0, 2><<<dim3(NTOK / 256, 6), 256, 0, stream>>>(
      hbuf, WkvrT, NTOK, 768, ka, nullptr, nullptr);
  wkv_phase1<<<BDIM * NCHUNK / 4, 256, 0, stream>>>(ka, va, decay, Sloc, Zloc);
  wkv_phase2<<<BDIM, 256, 0, stream>>>(Sloc, Zloc, decay, Sstart, Zstart);
  wkv_phase3<<<BDIM * NCHUNK / 4, 256, 0, stream>>>(ka, va, ra, decay, first,
                                                    Sstart, Zstart, a2);
  // x1 = x + a2@Wo fused with LN2 -> x1h (bf16), h2 (bf16); 512 blocks
  gemm7<<<NTOK / 64, 256, 0, stream>>>(a2, WoT, x, g2, b2, x1h, h2);

  // --- ChannelMix ---
  gemm3<128, 2, 2><<<dim3(NTOK / 256, 10), 256, 0, stream>>>(
      h2, Wkfr, NTOK, 1280, nullptr, g2buf, kk8);
  gemm6<<<dim3(NTOK / 128, 2), 256, 0, stream>>>(
      kk8, Wvf8, out, x1h, g2buf);
}

// Round 12
// 270.285 us; speedup vs baseline: 1.0633x; 1.0325x over previous
//
#include <hip/hip_runtime.h>
#include <hip/hip_bf16.h>
#include <math.h>

// Problem constants
#define TDIM 4096
#define CDIM 256
#define BDIM 8
#define NTOK (BDIM * TDIM)   // 32768 rows
#define HIDDIM 1024
#define NCHUNK 256
#define CHLEN 16             // 4096 / 256

typedef float f32x4 __attribute__((ext_vector_type(4)));
typedef __bf16 bf16x8 __attribute__((ext_vector_type(8)));
typedef __bf16 bf16x4 __attribute__((ext_vector_type(4)));

// async global->LDS, 16 B/lane, lands at wave-uniform base + lane*16
#define GLDS16(gp, lp) __builtin_amdgcn_global_load_lds( \
    (const __attribute__((address_space(1))) void*)(gp), \
    (__attribute__((address_space(3))) void*)(lp), 16, 0, 0)

// s_waitcnt imm: vmcnt[3:0] in [3:0], vmcnt[5:4] in [15:14], lgkm in [11:8]
#define WAITCNT_VM5  0x0F75
#define WAITCNT_VM2  0x0F72
#define WAITCNT_VM0  0x0F70

__device__ __forceinline__ float sigm(float v) { return 1.0f / (1.0f + __expf(-v)); }

// ---------------------------------------------------------------------------
// Weight pack: fp32 [K,N] -> transposed [N,K].
//   WoT    [256][256]  bf16
//   Wkvr8  [768][256]  fp8 = [Wk^T; Wv^T; Wr^T]
//   Wkfr8  [1280][256] fp8 = [Wkf^T; Wrf^T]
//   Wvf8   [256][1024] fp8
// ---------------------------------------------------------------------------
__global__ __launch_bounds__(256) void pack_weights(
    const float* __restrict__ Wk, const float* __restrict__ Wv,
    const float* __restrict__ Wr, const float* __restrict__ Wo,
    const float* __restrict__ Wkf, const float* __restrict__ Wvf,
    const float* __restrict__ Wrf,
    __bf16* __restrict__ WoT, unsigned char* __restrict__ Wkvr8,
    unsigned char* __restrict__ Wkfr8, unsigned char* __restrict__ Wvf8) {
  long long j = (long long)blockIdx.x * 256 + threadIdx.x;
  if (j < 49152) {            // Wkvr8: 4 fp8/thread
    const long long d = j * 4;
    const int n = (int)(d >> 8), k0 = (int)(d & 255);
    const float* src = (n < 256) ? Wk : (n < 512 ? Wv : Wr);
    const int nn = n & 255;
    int w = 0;
    w = __builtin_amdgcn_cvt_pk_fp8_f32(src[k0 * 256 + nn],
                                        src[(k0 + 1) * 256 + nn], w, false);
    w = __builtin_amdgcn_cvt_pk_fp8_f32(src[(k0 + 2) * 256 + nn],
                                        src[(k0 + 3) * 256 + nn], w, true);
    *(int*)&Wkvr8[d] = w;
    return;
  }
  j -= 49152;
  if (j < 65536) { int n = (int)(j >> 8), k = (int)(j & 255);
    WoT[j] = (__bf16)Wo[k * 256 + n]; return; }
  j -= 65536;
  if (j < 81920) {            // Wkfr8: 4 fp8/thread
    const long long d = j * 4;
    const int n = (int)(d >> 8), k0 = (int)(d & 255);
    float v0, v1, v2, v3;
    if (n < 1024) {
      v0 = Wkf[(long long)k0 * 1024 + n];       v1 = Wkf[(long long)(k0 + 1) * 1024 + n];
      v2 = Wkf[(long long)(k0 + 2) * 1024 + n]; v3 = Wkf[(long long)(k0 + 3) * 1024 + n];
    } else {
      const int m = n - 1024;
      v0 = Wrf[k0 * 256 + m];       v1 = Wrf[(k0 + 1) * 256 + m];
      v2 = Wrf[(k0 + 2) * 256 + m]; v3 = Wrf[(k0 + 3) * 256 + m];
    }
    int w = 0;
    w = __builtin_amdgcn_cvt_pk_fp8_f32(v0, v1, w, false);
    w = __builtin_amdgcn_cvt_pk_fp8_f32(v2, v3, w, true);
    *(int*)&Wkfr8[d] = w;
    return;
  }
  j -= 81920;
  if (j < 65536) {            // Wvf8 [256][1024]: 4 fp8/thread
    const long long d = j * 4;
    const int n = (int)(d >> 10), k0 = (int)(d & 1023);
    int w = 0;
    w = __builtin_amdgcn_cvt_pk_fp8_f32(Wvf[(long long)k0 * 256 + n],
                                        Wvf[(long long)(k0 + 1) * 256 + n], w, false);
    w = __builtin_amdgcn_cvt_pk_fp8_f32(Wvf[(long long)(k0 + 2) * 256 + n],
                                        Wvf[(long long)(k0 + 3) * 256 + n], w, true);
    *(int*)&Wvf8[d] = w;
    return;
  }
}

// ---------------------------------------------------------------------------
// LayerNorm over C=256: one wave per row, 4 rows/block, fp8 output.
// ---------------------------------------------------------------------------
__global__ __launch_bounds__(256) void ln_kernel(
    const float* __restrict__ x, const float* __restrict__ gamma,
    const float* __restrict__ beta, unsigned char* __restrict__ h8) {
  const int wave = threadIdx.x >> 6, lane = threadIdx.x & 63;
  const long long row = (long long)blockIdx.x * 4 + wave;
  const long long base = row * CDIM + lane * 4;
  const f32x4 v = *(const f32x4*)&x[base];
  float s = v[0] + v[1] + v[2] + v[3];
  float s2 = v[0]*v[0] + v[1]*v[1] + v[2]*v[2] + v[3]*v[3];
  #pragma unroll
  for (int o = 1; o < 64; o <<= 1) { s += __shfl_xor(s, o); s2 += __shfl_xor(s2, o); }
  const float mean = s * (1.0f / CDIM);
  const float var = s2 * (1.0f / CDIM) - mean * mean;
  const float rstd = rsqrtf(var + 1e-5f);
  const f32x4 g4 = *(const f32x4*)&gamma[lane * 4];
  const f32x4 b4 = *(const f32x4*)&beta[lane * 4];
  float o0 = (v[0] - mean) * rstd * g4[0] + b4[0];
  float o1 = (v[1] - mean) * rstd * g4[1] + b4[1];
  float o2 = (v[2] - mean) * rstd * g4[2] + b4[2];
  float o3 = (v[3] - mean) * rstd * g4[3] + b4[3];
  int w = 0;
  w = __builtin_amdgcn_cvt_pk_fp8_f32(o0, o1, w, false);
  w = __builtin_amdgcn_cvt_pk_fp8_f32(o2, o3, w, true);
  *(int*)&h8[base] = w;
}

// ---------------------------------------------------------------------------
// fp8 MFMA GEMM, K=256 (gemm6's verified staging/swizzle/fragment pattern).
// BM=128, BN=128, 4 waves 2x2, triple-buffered byte-LDS, PD2, vmcnt<=2.
// Accumulator TRANSPOSED (mfma(fb,fa)): lane (quad,mrow) reg r ->
//   row=mtile+mrow, col=ntile+quad*4+r.
// EPI 0: planar kvr store (plane = blockIdx.y>>1; 0:k 1:v 2:sigmoid->r)
// EPI 2: y<8: kk8 = fp8(relu(acc)^2) [stride 1024]; y>=8: g2 = sigmoid [256]
// ---------------------------------------------------------------------------
template <int EPI>
__global__ __launch_bounds__(256, 4) void gemm8(
    const unsigned char* __restrict__ A8, const unsigned char* __restrict__ B8,
    int M, __bf16* __restrict__ outH, __bf16* __restrict__ outH2,
    unsigned char* __restrict__ outC) {
  __shared__ unsigned char sA[3][128 * 32];
  __shared__ unsigned char sB[3][128 * 32];
  const int tid = threadIdx.x;
  const int wave = tid >> 6, lane = tid & 63;
  const int quad = lane >> 4, mrow = lane & 15;
  const long long bm = (long long)blockIdx.x * 128;
  const long long bn = (long long)blockIdx.y * 128;
  const int wm = (wave & 1) * 64, wn = (wave >> 1) * 64;
  const int srow = lane >> 1;                     // 0..31
  const int hs = (lane & 1) ^ ((lane >> 2) & 1);  // swizzled source half

  auto issue = [&](int g) {
    const int buf = g % 3;
    const long long k0 = (long long)g * 32;
    const int a0 = wave * 32;
    GLDS16(A8 + (bm + a0 + srow) * 256LL + k0 + hs * 16, &sA[buf][a0 * 32]);
    GLDS16(B8 + (bn + a0 + srow) * 256LL + k0 + hs * 16, &sB[buf][a0 * 32]);
  };

  f32x4 acc[4][4] = {};
  issue(0);
  issue(1);
  const int sw = (mrow >> 1) & 1;

  auto compute = [&](int i) {
    const int buf = i % 3;
    long long fa[4], fb[4];
    const int off = ((((quad >> 1) ^ sw) << 4) | ((quad & 1) << 3));
    #pragma unroll
    for (int mt = 0; mt < 4; mt++)
      fa[mt] = *(const long long*)&sA[buf][(wm + mt * 16 + mrow) * 32 + off];
    #pragma unroll
    for (int nt = 0; nt < 4; nt++)
      fb[nt] = *(const long long*)&sB[buf][(wn + nt * 16 + mrow) * 32 + off];
    #pragma unroll
    for (int mt = 0; mt < 4; mt++)
      #pragma unroll
      for (int nt = 0; nt < 4; nt++)
        acc[mt][nt] = __builtin_amdgcn_mfma_f32_16x16x32_fp8_fp8(fb[nt], fa[mt], acc[mt][nt], 0, 0, 0);
  };

  #pragma unroll 1
  for (int i = 0; i < 7; i++) {
    __builtin_amdgcn_s_waitcnt(WAITCNT_VM2);
    __builtin_amdgcn_s_barrier();
    if (i + 2 < 8) issue(i + 2);
    compute(i);
  }
  __builtin_amdgcn_s_waitcnt(WAITCNT_VM0);
  __builtin_amdgcn_s_barrier();
  compute(7);

  #pragma unroll
  for (int mt = 0; mt < 4; mt++) {
    #pragma unroll
    for (int nt = 0; nt < 4; nt++) {
      const long long row = bm + wm + mt * 16 + mrow;
      const long long colb = bn + wn + nt * 16 + quad * 4;
      const f32x4 a = acc[mt][nt];
      if (EPI == 0) {
        const int plane = blockIdx.y >> 1;
        __bf16* o = outH + (long long)plane * ((long long)M * 256);
        const long long c2 = colb & 255;
        bf16x4 v;
        if (plane == 2) {
          #pragma unroll
          for (int r = 0; r < 4; r++) v[r] = (__bf16)sigm(a[r]);
        } else {
          #pragma unroll
          for (int r = 0; r < 4; r++) v[r] = (__bf16)a[r];
        }
        *(bf16x4*)&o[row * 256 + c2] = v;
      } else {
        if (blockIdx.y < 8) {
          float t0 = a[0] > 0.0f ? a[0] : 0.0f;
          float t1 = a[1] > 0.0f ? a[1] : 0.0f;
          float t2 = a[2] > 0.0f ? a[2] : 0.0f;
          float t3 = a[3] > 0.0f ? a[3] : 0.0f;
          int w = 0;
          w = __builtin_amdgcn_cvt_pk_fp8_f32(t0 * t0, t1 * t1, w, false);
          w = __builtin_amdgcn_cvt_pk_fp8_f32(t2 * t2, t3 * t3, w, true);
          *(int*)&outC[row * 1024 + colb] = w;
        } else {
          bf16x4 v;
          #pragma unroll
          for (int r = 0; r < 4; r++) v[r] = (__bf16)sigm(a[r]);
          *(bf16x4*)&outH2[row * 256 + (colb - 1024)] = v;
        }
      }
    }
  }
}

// ---------------------------------------------------------------------------
// Fused x1 = x + a2@WoT (bf16 GEMM), LN2 -> h2 as FP8. BM=64 (512 blocks),
// BN=256; 4 waves each own 64 cols of all 64 rows. Triple-buffer PD2.
// ---------------------------------------------------------------------------
__global__ __launch_bounds__(256, 2) void gemm7(
    const __bf16* __restrict__ A, const __bf16* __restrict__ Bt,
    const float* __restrict__ x,
    const float* __restrict__ gammaP, const float* __restrict__ betaP,
    __bf16* __restrict__ x1h, unsigned char* __restrict__ h28) {
  constexpr int K = 256;
  __shared__ __bf16 sA[3][64 * 32];
  __shared__ __bf16 sB[3][256 * 32];
  __shared__ float redS[4][64], redQ[4][64];

  const int tid = threadIdx.x;
  const int wave = tid >> 6, lane = tid & 63;
  const int quad = lane >> 4, mrow = lane & 15;
  const long long bm = (long long)blockIdx.x * 64;
  const int wn = wave * 64;
  const int lrow = lane >> 2;
  const int lk = (lane & 3) * 8;

  auto issue = [&](int g) {
    const int buf = g % 3;
    const long long k0 = (long long)g * 32;
    GLDS16(A + (bm + wave * 16 + lrow) * (long long)K + k0 + lk,
           &sA[buf][(wave * 16) * 32]);
    #pragma unroll
    for (int bc = 0; bc < 4; bc++) {
      const int r0 = wave * 64 + bc * 16;
      GLDS16(Bt + (r0 + lrow) * (long long)K + k0 + lk, &sB[buf][r0 * 32]);
    }
  };

  f32x4 acc[4][4] = {};

  auto compute = [&](int g) {
    const int buf = g % 3;
    bf16x8 fa[4], fb[4];
    #pragma unroll
    for (int mt = 0; mt < 4; mt++)
      fa[mt] = *(const bf16x8*)&sA[buf][(mt * 16 + mrow) * 32 + quad * 8];
    #pragma unroll
    for (int nt = 0; nt < 4; nt++)
      fb[nt] = *(const bf16x8*)&sB[buf][(wn + nt * 16 + mrow) * 32 + quad * 8];
    #pragma unroll
    for (int mt = 0; mt < 4; mt++)
      #pragma unroll
      for (int nt = 0; nt < 4; nt++)
        acc[mt][nt] = __builtin_amdgcn_mfma_f32_16x16x32_bf16(fb[nt], fa[mt], acc[mt][nt], 0, 0, 0);
  };

  issue(0);
  issue(1);
  #pragma unroll 1
  for (int g = 0; g < 8; g++) {
    if (g == 7) {
      __builtin_amdgcn_s_waitcnt(WAITCNT_VM0);
    } else {
      __builtin_amdgcn_s_waitcnt(WAITCNT_VM5);
    }
    __builtin_amdgcn_s_barrier();
    if (g + 2 < 8) issue(g + 2);
    compute(g);
  }

  // residual add + LN partials
  float sum[4] = {0, 0, 0, 0}, sq[4] = {0, 0, 0, 0};
  #pragma unroll
  for (int mt = 0; mt < 4; mt++) {
    #pragma unroll
    for (int nt = 0; nt < 4; nt++) {
      const long long row = bm + mt * 16 + mrow;
      const long long colb = wn + nt * 16 + quad * 4;
      acc[mt][nt] += *(const f32x4*)&x[row * 256 + colb];
      #pragma unroll
      for (int r = 0; r < 4; r++) {
        sum[mt] += acc[mt][nt][r];
        sq[mt] += acc[mt][nt][r] * acc[mt][nt][r];
      }
    }
  }
  #pragma unroll
  for (int mt = 0; mt < 4; mt++) {
    sum[mt] += __shfl_xor(sum[mt], 16); sq[mt] += __shfl_xor(sq[mt], 16);
    sum[mt] += __shfl_xor(sum[mt], 32); sq[mt] += __shfl_xor(sq[mt], 32);
  }
  if (quad == 0) {
    #pragma unroll
    for (int mt = 0; mt < 4; mt++) {
      redS[wave][mt * 16 + mrow] = sum[mt];
      redQ[wave][mt * 16 + mrow] = sq[mt];
    }
  }
  __syncthreads();
  #pragma unroll
  for (int mt = 0; mt < 4; mt++) {
    const int rb = mt * 16 + mrow;
    const float ts = redS[0][rb] + redS[1][rb] + redS[2][rb] + redS[3][rb];
    const float tq = redQ[0][rb] + redQ[1][rb] + redQ[2][rb] + redQ[3][rb];
    const float mean = ts * (1.0f / 256.0f);
    const float rstd = rsqrtf(tq * (1.0f / 256.0f) - mean * mean + 1e-5f);
    const long long row = bm + rb;
    #pragma unroll
    for (int nt = 0; nt < 4; nt++) {
      const long long colb = wn + nt * 16 + quad * 4;
      const f32x4 g4 = *(const f32x4*)&gammaP[colb];
      const f32x4 b4 = *(const f32x4*)&betaP[colb];
      bf16x4 xo;
      float h0, h1, h2v, h3;
      {
        const float t0 = acc[mt][nt][0], t1 = acc[mt][nt][1];
        const float t2 = acc[mt][nt][2], t3 = acc[mt][nt][3];
        xo[0] = (__bf16)t0; xo[1] = (__bf16)t1; xo[2] = (__bf16)t2; xo[3] = (__bf16)t3;
        h0 = (t0 - mean) * rstd * g4[0] + b4[0];
        h1 = (t1 - mean) * rstd * g4[1] + b4[1];
        h2v = (t2 - mean) * rstd * g4[2] + b4[2];
        h3 = (t3 - mean) * rstd * g4[3] + b4[3];
      }
      *(bf16x4*)&x1h[row * 256 + colb] = xo;
      int w = 0;
      w = __builtin_amdgcn_cvt_pk_fp8_f32(h0, h1, w, false);
      w = __builtin_amdgcn_cvt_pk_fp8_f32(h2v, h3, w, true);
      *(int*)&h28[row * 256 + colb] = w;
    }
  }
}

// ---------------------------------------------------------------------------
// fp8 MFMA GEMM (K=1024): out[NTOK,256] = x1h + g2 * (kk8 @ Wvf8^T)
// (unchanged) BM=128, BN=128, triple-buffered byte-LDS, PD2.
// ---------------------------------------------------------------------------
__global__ __launch_bounds__(256, 4) void gemm6(
    const unsigned char* __restrict__ A8, const unsigned char* __restrict__ B8,
    float* __restrict__ outF, const __bf16* __restrict__ srcH,
    const __bf16* __restrict__ gate) {
  __shared__ unsigned char sA[3][128 * 32];
  __shared__ unsigned char sB[3][128 * 32];
  const int tid = threadIdx.x;
  const int wave = tid >> 6, lane = tid & 63;
  const int quad = lane >> 4, mrow = lane & 15;
  const long long bm = (long long)blockIdx.x * 128;
  const long long bn = (long long)blockIdx.y * 128;
  const int wm = (wave & 1) * 64, wn = (wave >> 1) * 64;
  const int srow = lane >> 1;
  const int hs = (lane & 1) ^ ((lane >> 2) & 1);

  auto issue = [&](int g) {
    const int buf = g % 3;
    const long long k0 = (long long)g * 32;
    const int a0 = wave * 32;
    GLDS16(A8 + (bm + a0 + srow) * 1024LL + k0 + hs * 16, &sA[buf][a0 * 32]);
    GLDS16(B8 + (bn + a0 + srow) * 1024LL + k0 + hs * 16, &sB[buf][a0 * 32]);
  };

  f32x4 acc[4][4] = {};
  issue(0);
  issue(1);
  const int sw = (mrow >> 1) & 1;

  auto compute = [&](int i) {
    const int buf = i % 3;
    long long fa[4], fb[4];
    const int off = ((((quad >> 1) ^ sw) << 4) | ((quad & 1) << 3));
    #pragma unroll
    for (int mt = 0; mt < 4; mt++)
      fa[mt] = *(const long long*)&sA[buf][(wm + mt * 16 + mrow) * 32 + off];
    #pragma unroll
    for (int nt = 0; nt < 4; nt++)
      fb[nt] = *(const long long*)&sB[buf][(wn + nt * 16 + mrow) * 32 + off];
    #pragma unroll
    for (int mt = 0; mt < 4; mt++)
      #pragma unroll
      for (int nt = 0; nt < 4; nt++)
        acc[mt][nt] = __builtin_amdgcn_mfma_f32_16x16x32_fp8_fp8(fb[nt], fa[mt], acc[mt][nt], 0, 0, 0);
  };

  #pragma unroll 1
  for (int i = 0; i < 31; i++) {
    __builtin_amdgcn_s_waitcnt(WAITCNT_VM2);
    __builtin_amdgcn_s_barrier();
    if (i + 2 < 32) issue(i + 2);
    compute(i);
  }
  __builtin_amdgcn_s_waitcnt(WAITCNT_VM0);
  __builtin_amdgcn_s_barrier();
  compute(31);

  #pragma unroll
  for (int mt = 0; mt < 4; mt++) {
    #pragma unroll
    for (int nt = 0; nt < 4; nt++) {
      const long long row = bm + wm + mt * 16 + mrow;
      const long long colb = bn + wn + nt * 16 + quad * 4;
      const long long idx = row * 256 + colb;
      const f32x4 a = acc[mt][nt];
      const bf16x4 s4 = *(const bf16x4*)&srcH[idx];
      const bf16x4 g4 = *(const bf16x4*)&gate[idx];
      f32x4 v;
      #pragma unroll
      for (int r = 0; r < 4; r++) v[r] = (float)s4[r] + (float)g4[r] * a[r];
      *(f32x4*)&outF[idx] = v;
    }
  }
}

// ---------------------------------------------------------------------------
// WKV chunked scan on planar k/v/sr arrays. NCHUNK=256 (CHLEN=16) -> 512
// blocks = 2/CU. Direct fp32 recurrence (exponents bounded).
// ---------------------------------------------------------------------------
__global__ __launch_bounds__(256) void wkv_phase1(
    const __bf16* __restrict__ ka, const __bf16* __restrict__ va,
    const float* __restrict__ decay,
    float* __restrict__ Sloc, float* __restrict__ Zloc) {
  const int wave = threadIdx.x >> 6, lane = threadIdx.x & 63;
  const int gi = blockIdx.x * 4 + wave;          // 0..2047
  const int b = gi >> 8, chunk = gi & (NCHUNK - 1);
  const int c0 = lane * 4;
  const f32x4 w4 = *(const f32x4*)&decay[c0];
  f32x4 ew;
  #pragma unroll
  for (int r = 0; r < 4; r++) ew[r] = __expf(w4[r] * (1.0f / TDIM));
  f32x4 S = {0,0,0,0}, Z = {0,0,0,0};
  long long base = ((long long)b * TDIM + (long long)chunk * CHLEN) * 256 + c0;
  #pragma unroll 4
  for (int t = 0; t < CHLEN; t++) {
    const bf16x4 k4 = *(const bf16x4*)&ka[base + (long long)t * 256];
    const bf16x4 v4 = *(const bf16x4*)&va[base + (long long)t * 256];
    #pragma unroll
    for (int r = 0; r < 4; r++) {
      const float ek = __expf((float)k4[r]);
      S[r] = ew[r] * S[r] + ek * (float)v4[r];
      Z[r] = ew[r] * Z[r] + ek;
    }
  }
  const long long o = (long long)gi * 256 + c0;
  *(f32x4*)&Sloc[o] = S;
  *(f32x4*)&Zloc[o] = Z;
}

__global__ __launch_bounds__(256) void wkv_phase2(
    const float* __restrict__ Sloc, const float* __restrict__ Zloc,
    const float* __restrict__ decay,
    float* __restrict__ Sstart, float* __restrict__ Zstart) {
  const int idx = blockIdx.x * 256 + threadIdx.x;  // 0..2047
  const int c = idx & 255;
  const int b = idx >> 8;
  const float w = decay[c] * (1.0f / TDIM);
  const float ewL = __expf(w * (float)CHLEN);
  float S = 0.0f, Z = 0.0f;
  for (int j = 0; j < NCHUNK; j++) {
    const long long o = ((long long)b * NCHUNK + j) * 256 + c;
    Sstart[o] = S;
    Zstart[o] = Z;
    S = ewL * S + Sloc[o];
    Z = ewL * Z + Zloc[o];
  }
}

__global__ __launch_bounds__(256) void wkv_phase3(
    const __bf16* __restrict__ ka, const __bf16* __restrict__ va,
    const __bf16* __restrict__ ra,   // holds sigmoid(r)
    const float* __restrict__ decay, const float* __restrict__ first,
    const float* __restrict__ Sstart, const float* __restrict__ Zstart,
    __bf16* __restrict__ a2) {
  const int wave = threadIdx.x >> 6, lane = threadIdx.x & 63;
  const int gi = blockIdx.x * 4 + wave;
  const int b = gi >> 8, chunk = gi & (NCHUNK - 1);
  const int c0 = lane * 4;
  const f32x4 w4 = *(const f32x4*)&decay[c0];
  const f32x4 u4 = *(const f32x4*)&first[c0];
  f32x4 ew, eu;
  #pragma unroll
  for (int r = 0; r < 4; r++) {
    ew[r] = __expf(w4[r] * (1.0f / TDIM));
    eu[r] = __expf(u4[r] * (1.0f / TDIM));
  }
  const long long so = (long long)gi * 256 + c0;
  f32x4 S = *(const f32x4*)&Sstart[so];
  f32x4 Z = *(const f32x4*)&Zstart[so];
  long long base = ((long long)b * TDIM + (long long)chunk * CHLEN) * 256 + c0;
  #pragma unroll 2
  for (int t = 0; t < CHLEN; t++) {
    const long long p = base + (long long)t * 256;
    const bf16x4 k4 = *(const bf16x4*)&ka[p];
    const bf16x4 v4 = *(const bf16x4*)&va[p];
    const bf16x4 r4 = *(const bf16x4*)&ra[p];
    bf16x4 o;
    #pragma unroll
    for (int r = 0; r < 4; r++) {
      const float ek = __expf((float)k4[r]);
      const float E = eu[r] * ek;
      const float y = (S[r] + E * (float)v4[r]) / (Z[r] + E);
      o[r] = (__bf16)((float)r4[r] * y);
      S[r] = ew[r] * S[r] + ek * (float)v4[r];
      Z[r] = ew[r] * Z[r] + ek;
    }
    *(bf16x4*)&a2[p] = o;
  }
}

// ---------------------------------------------------------------------------
// Workspace layout (peak ~169 MB):
//   [0)    ka 16M | [16M) va | [32M) ra (=sigmoid r)
//   [48M)  a2 16M -> reused as g2buf after gemm7
//   [64M)  h8 (fp8 8M) -> reused as h28 (fp8, written by gemm7)
//   [80M)  x1h 16M
//   [96M)  kk8 (fp8, 32M)
//   [128M) scan state S/Z (4 x 2M)
//   [160M) packed weights (~0.9 MB)
// ---------------------------------------------------------------------------
extern "C" void kernel_launch(void* const* d_in, const int* in_sizes, int n_in,
                              void* d_out, int out_size, void* d_ws, size_t ws_size,
                              hipStream_t stream) {
  const float* x     = (const float*)d_in[0];
  const float* Wk    = (const float*)d_in[1];
  const float* Wv    = (const float*)d_in[2];
  const float* Wr    = (const float*)d_in[3];
  const float* Wo    = (const float*)d_in[4];
  const float* Wkf   = (const float*)d_in[5];
  const float* Wvf   = (const float*)d_in[6];
  const float* Wrf   = (const float*)d_in[7];
  const float* g1    = (const float*)d_in[8];
  const float* b1    = (const float*)d_in[9];
  const float* g2    = (const float*)d_in[10];
  const float* b2    = (const float*)d_in[11];
  const float* decay = (const float*)d_in[12];
  const float* first = (const float*)d_in[13];
  float* out = (float*)d_out;
  char* ws = (char*)d_ws;

  __bf16* ka     = (__bf16*)(ws + 0);
  __bf16* va     = (__bf16*)(ws + 16777216LL);
  __bf16* ra     = (__bf16*)(ws + 33554432LL);
  __bf16* a2     = (__bf16*)(ws + 50331648LL);
  __bf16* g2buf  = (__bf16*)(ws + 50331648LL);      // reuses a2 (dead after gemm7)
  unsigned char* h8  = (unsigned char*)(ws + 67108864LL);
  unsigned char* h28 = (unsigned char*)(ws + 67108864LL);  // reuses h8 (dead)
  __bf16* x1h    = (__bf16*)(ws + 83886080LL);
  unsigned char* kk8 = (unsigned char*)(ws + 100663296LL);
  float*  Sloc   = (float*)(ws + 134217728LL);
  float*  Zloc   = (float*)(ws + 137363456LL);
  float*  Sstart = (float*)(ws + 140509184LL);
  float*  Zstart = (float*)(ws + 143654912LL);
  __bf16* WoT    = (__bf16*)(ws + 167772160LL);
  unsigned char* Wkvr8 = (unsigned char*)(ws + 167903232LL);
  unsigned char* Wkfr8 = (unsigned char*)(ws + 168099840LL);
  unsigned char* Wvf8  = (unsigned char*)(ws + 168427520LL);

  pack_weights<<<1024, 256, 0, stream>>>(Wk, Wv, Wr, Wo, Wkf, Wvf, Wrf,
                                         WoT, Wkvr8, Wkfr8, Wvf8);

  // --- SpatialMix ---
  ln_kernel<<<NTOK / 4, 256, 0, stream>>>(x, g1, b1, h8);
  gemm8<0><<<dim3(NTOK / 128, 6), 256, 0, stream>>>(
      h8, Wkvr8, NTOK, ka, nullptr, nullptr);
  wkv_phase1<<<BDIM * NCHUNK / 4, 256, 0, stream>>>(ka, va, decay, Sloc, Zloc);
  wkv_phase2<<<BDIM, 256, 0, stream>>>(Sloc, Zloc, decay, Sstart, Zstart);
  wkv_phase3<<<BDIM * NCHUNK / 4, 256, 0, stream>>>(ka, va, ra, decay, first,
                                                    Sstart, Zstart, a2);
  // x1 = x + a2@Wo fused with LN2 -> x1h (bf16), h28 (fp8)
  gemm7<<<NTOK / 64, 256, 0, stream>>>(a2, WoT, x, g2, b2, x1h, h28);

  // --- ChannelMix ---
  gemm8<2><<<dim3(NTOK / 128, 10), 256, 0, stream>>>(
      h28, Wkfr8, NTOK, nullptr, g2buf, kk8);
  gemm6<<<dim3(NTOK / 128, 2), 256, 0, stream>>>(
      kk8, Wvf8, out, x1h, g2buf);
}

// Round 13
// 251.427 us; speedup vs baseline: 1.1431x; 1.0750x over previous
//
#include <hip/hip_runtime.h>
#include <hip/hip_bf16.h>
#include <math.h>

// Problem constants
#define TDIM 4096
#define CDIM 256
#define BDIM 8
#define NTOK (BDIM * TDIM)   // 32768 rows
#define HIDDIM 1024
#define NCHUNK 256
#define CHLEN 16             // 4096 / 256

typedef float f32x4 __attribute__((ext_vector_type(4)));
typedef __bf16 bf16x8 __attribute__((ext_vector_type(8)));
typedef __bf16 bf16x4 __attribute__((ext_vector_type(4)));
typedef long long i64x2 __attribute__((ext_vector_type(2)));

// async global->LDS, 16 B/lane, lands at wave-uniform base + lane*16
#define GLDS16(gp, lp) __builtin_amdgcn_global_load_lds( \
    (const __attribute__((address_space(1))) void*)(gp), \
    (__attribute__((address_space(3))) void*)(lp), 16, 0, 0)

// s_waitcnt imm: vmcnt[3:0] in [3:0], vmcnt[5:4] in [15:14], lgkm in [11:8]
#define WAITCNT_VM5  0x0F75
#define WAITCNT_VM4  0x0F74
#define WAITCNT_VM0  0x0F70

__device__ __forceinline__ float sigm(float v) { return 1.0f / (1.0f + __expf(-v)); }

// fp8 k-permutation within each 64-k group: k = p*64 + c*32 + q*8 + j
// -> byte position p*64 + q*16 + c*8 + j. A lane's b128 at row*64+q*16 then
// holds [chunk0 frag | chunk1 frag] for MFMA k=quad*8..+8 of both 32-chunks.
__device__ __forceinline__ int permk(int k) {
  return (k & ~63) + (((k >> 3) & 3) << 4) + (((k >> 5) & 1) << 3) + (k & 7);
}

// ---------------------------------------------------------------------------
// Weight pack: fp32 [K,N] -> transposed [N,K], fp8 k-permuted.
//   WoT    [256][256]  bf16
//   Wkvr8  [768][256]  fp8 = [Wk^T; Wv^T; Wr^T]
//   Wkfr8  [1280][256] fp8 = [Wkf^T; Wrf^T]
//   Wvf8   [256][1024] fp8
// ---------------------------------------------------------------------------
__global__ __launch_bounds__(256) void pack_weights(
    const float* __restrict__ Wk, const float* __restrict__ Wv,
    const float* __restrict__ Wr, const float* __restrict__ Wo,
    const float* __restrict__ Wkf, const float* __restrict__ Wvf,
    const float* __restrict__ Wrf,
    __bf16* __restrict__ WoT, unsigned char* __restrict__ Wkvr8,
    unsigned char* __restrict__ Wkfr8, unsigned char* __restrict__ Wvf8) {
  long long j = (long long)blockIdx.x * 256 + threadIdx.x;
  if (j < 49152) {            // Wkvr8: 4 fp8/thread
    const long long d = j * 4;
    const int n = (int)(d >> 8), k0 = (int)(d & 255);
    const float* src = (n < 256) ? Wk : (n < 512 ? Wv : Wr);
    const int nn = n & 255;
    int w = 0;
    w = __builtin_amdgcn_cvt_pk_fp8_f32(src[k0 * 256 + nn],
                                        src[(k0 + 1) * 256 + nn], w, false);
    w = __builtin_amdgcn_cvt_pk_fp8_f32(src[(k0 + 2) * 256 + nn],
                                        src[(k0 + 3) * 256 + nn], w, true);
    *(int*)&Wkvr8[(long long)n * 256 + permk(k0)] = w;
    return;
  }
  j -= 49152;
  if (j < 65536) { int n = (int)(j >> 8), k = (int)(j & 255);
    WoT[j] = (__bf16)Wo[k * 256 + n]; return; }
  j -= 65536;
  if (j < 81920) {            // Wkfr8: 4 fp8/thread
    const long long d = j * 4;
    const int n = (int)(d >> 8), k0 = (int)(d & 255);
    float v0, v1, v2, v3;
    if (n < 1024) {
      v0 = Wkf[(long long)k0 * 1024 + n];       v1 = Wkf[(long long)(k0 + 1) * 1024 + n];
      v2 = Wkf[(long long)(k0 + 2) * 1024 + n]; v3 = Wkf[(long long)(k0 + 3) * 1024 + n];
    } else {
      const int m = n - 1024;
      v0 = Wrf[k0 * 256 + m];       v1 = Wrf[(k0 + 1) * 256 + m];
      v2 = Wrf[(k0 + 2) * 256 + m]; v3 = Wrf[(k0 + 3) * 256 + m];
    }
    int w = 0;
    w = __builtin_amdgcn_cvt_pk_fp8_f32(v0, v1, w, false);
    w = __builtin_amdgcn_cvt_pk_fp8_f32(v2, v3, w, true);
    *(int*)&Wkfr8[(long long)n * 256 + permk(k0)] = w;
    return;
  }
  j -= 81920;
  if (j < 65536) {            // Wvf8 [256][1024]: 4 fp8/thread
    const long long d = j * 4;
    const int n = (int)(d >> 10), k0 = (int)(d & 1023);
    int w = 0;
    w = __builtin_amdgcn_cvt_pk_fp8_f32(Wvf[(long long)k0 * 256 + n],
                                        Wvf[(long long)(k0 + 1) * 256 + n], w, false);
    w = __builtin_amdgcn_cvt_pk_fp8_f32(Wvf[(long long)(k0 + 2) * 256 + n],
                                        Wvf[(long long)(k0 + 3) * 256 + n], w, true);
    *(int*)&Wvf8[(long long)n * 1024 + permk(k0)] = w;
    return;
  }
}

// ---------------------------------------------------------------------------
// LayerNorm over C=256: one wave per row, fp8 k-permuted output.
// ---------------------------------------------------------------------------
__global__ __launch_bounds__(256) void ln_kernel(
    const float* __restrict__ x, const float* __restrict__ gamma,
    const float* __restrict__ beta, unsigned char* __restrict__ h8) {
  const int wave = threadIdx.x >> 6, lane = threadIdx.x & 63;
  const long long row = (long long)blockIdx.x * 4 + wave;
  const long long base = row * CDIM + lane * 4;
  const f32x4 v = *(const f32x4*)&x[base];
  float s = v[0] + v[1] + v[2] + v[3];
  float s2 = v[0]*v[0] + v[1]*v[1] + v[2]*v[2] + v[3]*v[3];
  #pragma unroll
  for (int o = 1; o < 64; o <<= 1) { s += __shfl_xor(s, o); s2 += __shfl_xor(s2, o); }
  const float mean = s * (1.0f / CDIM);
  const float var = s2 * (1.0f / CDIM) - mean * mean;
  const float rstd = rsqrtf(var + 1e-5f);
  const f32x4 g4 = *(const f32x4*)&gamma[lane * 4];
  const f32x4 b4 = *(const f32x4*)&beta[lane * 4];
  float o0 = (v[0] - mean) * rstd * g4[0] + b4[0];
  float o1 = (v[1] - mean) * rstd * g4[1] + b4[1];
  float o2 = (v[2] - mean) * rstd * g4[2] + b4[2];
  float o3 = (v[3] - mean) * rstd * g4[3] + b4[3];
  int w = 0;
  w = __builtin_amdgcn_cvt_pk_fp8_f32(o0, o1, w, false);
  w = __builtin_amdgcn_cvt_pk_fp8_f32(o2, o3, w, true);
  *(int*)&h8[row * CDIM + permk(lane * 4)] = w;
}

// ---------------------------------------------------------------------------
// fp8 MFMA GEMM with k-permuted operands and b128 fragment reads.
// BM=128, BN=128, 4 waves 2x2; LDS rows = 64 B (one 64-k stage granule);
// triple-buffered, PD2, raw s_barrier + vmcnt<=4. Per stage-iter each lane
// does 8 ds_read_b128 feeding 32 MFMAs (2 k-chunks).
// Accumulator TRANSPOSED (mfma(fb,fa)): lane (quad,mrow) reg r ->
//   row=mtile+mrow, col=ntile+quad*4+r.
// EPI 0: planar kvr store (plane = blockIdx.y>>1; 0:k 1:v 2:sigmoid->r)
// EPI 2: y<8: kk8 = fp8(relu(acc)^2), k-permuted [stride 1024];
//        y>=8: g2 = sigmoid (bf16) [stride 256]
// EPI 3: f32 out = srcH + gate * acc   (final)
// ---------------------------------------------------------------------------
template <int K, int EPI>
__global__ __launch_bounds__(256, 3) void gemm9(
    const unsigned char* __restrict__ A8, const unsigned char* __restrict__ B8,
    int M, __bf16* __restrict__ outH, __bf16* __restrict__ outH2,
    unsigned char* __restrict__ outC,
    float* __restrict__ outF, const __bf16* __restrict__ srcH,
    const __bf16* __restrict__ gate) {
  constexpr int NIT = K / 64;
  __shared__ unsigned char sA[3][128 * 64];
  __shared__ unsigned char sB[3][128 * 64];
  const int tid = threadIdx.x;
  const int wave = tid >> 6, lane = tid & 63;
  const int quad = lane >> 4, mrow = lane & 15;
  const long long bm = (long long)blockIdx.x * 128;
  const long long bn = (long long)blockIdx.y * 128;
  const int wm = (wave & 1) * 64, wn = (wave >> 1) * 64;
  const int srow = lane >> 2;          // 0..15 (4 lanes per 64-B row)
  const int o16 = (lane & 3) * 16;

  auto issue = [&](int g) {
    const int buf = g % 3;
    const long long k0 = (long long)g * 64;
    const int a0 = wave * 32;
    GLDS16(A8 + (bm + a0 + srow) * (long long)K + k0 + o16, &sA[buf][a0 * 64]);
    GLDS16(A8 + (bm + a0 + 16 + srow) * (long long)K + k0 + o16, &sA[buf][(a0 + 16) * 64]);
    GLDS16(B8 + (bn + a0 + srow) * (long long)K + k0 + o16, &sB[buf][a0 * 64]);
    GLDS16(B8 + (bn + a0 + 16 + srow) * (long long)K + k0 + o16, &sB[buf][(a0 + 16) * 64]);
  };

  f32x4 acc[4][4] = {};
  issue(0);
  if (NIT > 1) issue(1);

  auto compute = [&](int g) {
    const int buf = g % 3;
    i64x2 fa[4], fb[4];
    #pragma unroll
    for (int mt = 0; mt < 4; mt++)
      fa[mt] = *(const i64x2*)&sA[buf][(wm + mt * 16 + mrow) * 64 + quad * 16];
    #pragma unroll
    for (int nt = 0; nt < 4; nt++)
      fb[nt] = *(const i64x2*)&sB[buf][(wn + nt * 16 + mrow) * 64 + quad * 16];
    #pragma unroll
    for (int c = 0; c < 2; c++)
      #pragma unroll
      for (int mt = 0; mt < 4; mt++)
        #pragma unroll
        for (int nt = 0; nt < 4; nt++)
          acc[mt][nt] = __builtin_amdgcn_mfma_f32_16x16x32_fp8_fp8(
              fb[nt][c], fa[mt][c], acc[mt][nt], 0, 0, 0);
  };

  #pragma unroll 1
  for (int g = 0; g < NIT; g++) {
    if (g == NIT - 1) {
      __builtin_amdgcn_s_waitcnt(WAITCNT_VM0);
    } else {
      __builtin_amdgcn_s_waitcnt(WAITCNT_VM4);
    }
    __builtin_amdgcn_s_barrier();
    if (g + 2 < NIT) issue(g + 2);
    compute(g);
  }

  #pragma unroll
  for (int mt = 0; mt < 4; mt++) {
    #pragma unroll
    for (int nt = 0; nt < 4; nt++) {
      const long long row = bm + wm + mt * 16 + mrow;
      const long long colb = bn + wn + nt * 16 + quad * 4;
      const f32x4 a = acc[mt][nt];
      if (EPI == 0) {
        const int plane = blockIdx.y >> 1;
        __bf16* o = outH + (long long)plane * ((long long)M * 256);
        const long long c2 = colb & 255;
        bf16x4 v;
        if (plane == 2) {
          #pragma unroll
          for (int r = 0; r < 4; r++) v[r] = (__bf16)sigm(a[r]);
        } else {
          #pragma unroll
          for (int r = 0; r < 4; r++) v[r] = (__bf16)a[r];
        }
        *(bf16x4*)&o[row * 256 + c2] = v;
      } else if (EPI == 2) {
        if (blockIdx.y < 8) {
          float t0 = a[0] > 0.0f ? a[0] : 0.0f;
          float t1 = a[1] > 0.0f ? a[1] : 0.0f;
          float t2 = a[2] > 0.0f ? a[2] : 0.0f;
          float t3 = a[3] > 0.0f ? a[3] : 0.0f;
          int w = 0;
          w = __builtin_amdgcn_cvt_pk_fp8_f32(t0 * t0, t1 * t1, w, false);
          w = __builtin_amdgcn_cvt_pk_fp8_f32(t2 * t2, t3 * t3, w, true);
          *(int*)&outC[row * 1024 + permk((int)colb)] = w;
        } else {
          bf16x4 v;
          #pragma unroll
          for (int r = 0; r < 4; r++) v[r] = (__bf16)sigm(a[r]);
          *(bf16x4*)&outH2[row * 256 + (colb - 1024)] = v;
        }
      } else {
        const long long idx = row * 256 + colb;
        const bf16x4 s4 = *(const bf16x4*)&srcH[idx];
        const bf16x4 g4 = *(const bf16x4*)&gate[idx];
        f32x4 v;
        #pragma unroll
        for (int r = 0; r < 4; r++) v[r] = (float)s4[r] + (float)g4[r] * a[r];
        *(f32x4*)&outF[idx] = v;
      }
    }
  }
}

// ---------------------------------------------------------------------------
// Fused x1 = x + a2@WoT (bf16 GEMM), LN2 -> h28 as fp8 (k-permuted).
// BM=64 (512 blocks), BN=256; triple-buffer PD2.
// ---------------------------------------------------------------------------
__global__ __launch_bounds__(256, 2) void gemm7(
    const __bf16* __restrict__ A, const __bf16* __restrict__ Bt,
    const float* __restrict__ x,
    const float* __restrict__ gammaP, const float* __restrict__ betaP,
    __bf16* __restrict__ x1h, unsigned char* __restrict__ h28) {
  constexpr int K = 256;
  __shared__ __bf16 sA[3][64 * 32];
  __shared__ __bf16 sB[3][256 * 32];
  __shared__ float redS[4][64], redQ[4][64];

  const int tid = threadIdx.x;
  const int wave = tid >> 6, lane = tid & 63;
  const int quad = lane >> 4, mrow = lane & 15;
  const long long bm = (long long)blockIdx.x * 64;
  const int wn = wave * 64;
  const int lrow = lane >> 2;
  const int lk = (lane & 3) * 8;

  auto issue = [&](int g) {
    const int buf = g % 3;
    const long long k0 = (long long)g * 32;
    GLDS16(A + (bm + wave * 16 + lrow) * (long long)K + k0 + lk,
           &sA[buf][(wave * 16) * 32]);
    #pragma unroll
    for (int bc = 0; bc < 4; bc++) {
      const int r0 = wave * 64 + bc * 16;
      GLDS16(Bt + (r0 + lrow) * (long long)K + k0 + lk, &sB[buf][r0 * 32]);
    }
  };

  f32x4 acc[4][4] = {};

  auto compute = [&](int g) {
    const int buf = g % 3;
    bf16x8 fa[4], fb[4];
    #pragma unroll
    for (int mt = 0; mt < 4; mt++)
      fa[mt] = *(const bf16x8*)&sA[buf][(mt * 16 + mrow) * 32 + quad * 8];
    #pragma unroll
    for (int nt = 0; nt < 4; nt++)
      fb[nt] = *(const bf16x8*)&sB[buf][(wn + nt * 16 + mrow) * 32 + quad * 8];
    #pragma unroll
    for (int mt = 0; mt < 4; mt++)
      #pragma unroll
      for (int nt = 0; nt < 4; nt++)
        acc[mt][nt] = __builtin_amdgcn_mfma_f32_16x16x32_bf16(fb[nt], fa[mt], acc[mt][nt], 0, 0, 0);
  };

  issue(0);
  issue(1);
  #pragma unroll 1
  for (int g = 0; g < 8; g++) {
    if (g == 7) {
      __builtin_amdgcn_s_waitcnt(WAITCNT_VM0);
    } else {
      __builtin_amdgcn_s_waitcnt(WAITCNT_VM5);
    }
    __builtin_amdgcn_s_barrier();
    if (g + 2 < 8) issue(g + 2);
    compute(g);
  }

  // residual add + LN partials
  float sum[4] = {0, 0, 0, 0}, sq[4] = {0, 0, 0, 0};
  #pragma unroll
  for (int mt = 0; mt < 4; mt++) {
    #pragma unroll
    for (int nt = 0; nt < 4; nt++) {
      const long long row = bm + mt * 16 + mrow;
      const long long colb = wn + nt * 16 + quad * 4;
      acc[mt][nt] += *(const f32x4*)&x[row * 256 + colb];
      #pragma unroll
      for (int r = 0; r < 4; r++) {
        sum[mt] += acc[mt][nt][r];
        sq[mt] += acc[mt][nt][r] * acc[mt][nt][r];
      }
    }
  }
  #pragma unroll
  for (int mt = 0; mt < 4; mt++) {
    sum[mt] += __shfl_xor(sum[mt], 16); sq[mt] += __shfl_xor(sq[mt], 16);
    sum[mt] += __shfl_xor(sum[mt], 32); sq[mt] += __shfl_xor(sq[mt], 32);
  }
  if (quad == 0) {
    #pragma unroll
    for (int mt = 0; mt < 4; mt++) {
      redS[wave][mt * 16 + mrow] = sum[mt];
      redQ[wave][mt * 16 + mrow] = sq[mt];
    }
  }
  __syncthreads();
  #pragma unroll
  for (int mt = 0; mt < 4; mt++) {
    const int rb = mt * 16 + mrow;
    const float ts = redS[0][rb] + redS[1][rb] + redS[2][rb] + redS[3][rb];
    const float tq = redQ[0][rb] + redQ[1][rb] + redQ[2][rb] + redQ[3][rb];
    const float mean = ts * (1.0f / 256.0f);
    const float rstd = rsqrtf(tq * (1.0f / 256.0f) - mean * mean + 1e-5f);
    const long long row = bm + rb;
    #pragma unroll
    for (int nt = 0; nt < 4; nt++) {
      const long long colb = wn + nt * 16 + quad * 4;
      const f32x4 g4 = *(const f32x4*)&gammaP[colb];
      const f32x4 b4 = *(const f32x4*)&betaP[colb];
      bf16x4 xo;
      const float t0 = acc[mt][nt][0], t1 = acc[mt][nt][1];
      const float t2 = acc[mt][nt][2], t3 = acc[mt][nt][3];
      xo[0] = (__bf16)t0; xo[1] = (__bf16)t1; xo[2] = (__bf16)t2; xo[3] = (__bf16)t3;
      const float h0 = (t0 - mean) * rstd * g4[0] + b4[0];
      const float h1 = (t1 - mean) * rstd * g4[1] + b4[1];
      const float h2v = (t2 - mean) * rstd * g4[2] + b4[2];
      const float h3 = (t3 - mean) * rstd * g4[3] + b4[3];
      *(bf16x4*)&x1h[row * 256 + colb] = xo;
      int w = 0;
      w = __builtin_amdgcn_cvt_pk_fp8_f32(h0, h1, w, false);
      w = __builtin_amdgcn_cvt_pk_fp8_f32(h2v, h3, w, true);
      *(int*)&h28[row * 256 + permk((int)colb)] = w;
    }
  }
}

// ---------------------------------------------------------------------------
// WKV chunked scan on planar k/v/sr arrays. NCHUNK=256 (CHLEN=16).
// ---------------------------------------------------------------------------
__global__ __launch_bounds__(256) void wkv_phase1(
    const __bf16* __restrict__ ka, const __bf16* __restrict__ va,
    const float* __restrict__ decay,
    float* __restrict__ Sloc, float* __restrict__ Zloc) {
  const int wave = threadIdx.x >> 6, lane = threadIdx.x & 63;
  const int gi = blockIdx.x * 4 + wave;          // 0..2047
  const int b = gi >> 8, chunk = gi & (NCHUNK - 1);
  const int c0 = lane * 4;
  const f32x4 w4 = *(const f32x4*)&decay[c0];
  f32x4 ew;
  #pragma unroll
  for (int r = 0; r < 4; r++) ew[r] = __expf(w4[r] * (1.0f / TDIM));
  f32x4 S = {0,0,0,0}, Z = {0,0,0,0};
  long long base = ((long long)b * TDIM + (long long)chunk * CHLEN) * 256 + c0;
  #pragma unroll 4
  for (int t = 0; t < CHLEN; t++) {
    const bf16x4 k4 = *(const bf16x4*)&ka[base + (long long)t * 256];
    const bf16x4 v4 = *(const bf16x4*)&va[base + (long long)t * 256];
    #pragma unroll
    for (int r = 0; r < 4; r++) {
      const float ek = __expf((float)k4[r]);
      S[r] = ew[r] * S[r] + ek * (float)v4[r];
      Z[r] = ew[r] * Z[r] + ek;
    }
  }
  const long long o = (long long)gi * 256 + c0;
  *(f32x4*)&Sloc[o] = S;
  *(f32x4*)&Zloc[o] = Z;
}

__global__ __launch_bounds__(256) void wkv_phase2(
    const float* __restrict__ Sloc, const float* __restrict__ Zloc,
    const float* __restrict__ decay,
    float* __restrict__ Sstart, float* __restrict__ Zstart) {
  const int idx = blockIdx.x * 256 + threadIdx.x;  // 0..2047
  const int c = idx & 255;
  const int b = idx >> 8;
  const float w = decay[c] * (1.0f / TDIM);
  const float ewL = __expf(w * (float)CHLEN);
  float S = 0.0f, Z = 0.0f;
  for (int j = 0; j < NCHUNK; j++) {
    const long long o = ((long long)b * NCHUNK + j) * 256 + c;
    Sstart[o] = S;
    Zstart[o] = Z;
    S = ewL * S + Sloc[o];
    Z = ewL * Z + Zloc[o];
  }
}

__global__ __launch_bounds__(256) void wkv_phase3(
    const __bf16* __restrict__ ka, const __bf16* __restrict__ va,
    const __bf16* __restrict__ ra,   // holds sigmoid(r)
    const float* __restrict__ decay, const float* __restrict__ first,
    const float* __restrict__ Sstart, const float* __restrict__ Zstart,
    __bf16* __restrict__ a2) {
  const int wave = threadIdx.x >> 6, lane = threadIdx.x & 63;
  const int gi = blockIdx.x * 4 + wave;
  const int b = gi >> 8, chunk = gi & (NCHUNK - 1);
  const int c0 = lane * 4;
  const f32x4 w4 = *(const f32x4*)&decay[c0];
  const f32x4 u4 = *(const f32x4*)&first[c0];
  f32x4 ew, eu;
  #pragma unroll
  for (int r = 0; r < 4; r++) {
    ew[r] = __expf(w4[r] * (1.0f / TDIM));
    eu[r] = __expf(u4[r] * (1.0f / TDIM));
  }
  const long long so = (long long)gi * 256 + c0;
  f32x4 S = *(const f32x4*)&Sstart[so];
  f32x4 Z = *(const f32x4*)&Zstart[so];
  long long base = ((long long)b * TDIM + (long long)chunk * CHLEN) * 256 + c0;
  #pragma unroll 2
  for (int t = 0; t < CHLEN; t++) {
    const long long p = base + (long long)t * 256;
    const bf16x4 k4 = *(const bf16x4*)&ka[p];
    const bf16x4 v4 = *(const bf16x4*)&va[p];
    const bf16x4 r4 = *(const bf16x4*)&ra[p];
    bf16x4 o;
    #pragma unroll
    for (int r = 0; r < 4; r++) {
      const float ek = __expf((float)k4[r]);
      const float E = eu[r] * ek;
      const float y = (S[r] + E * (float)v4[r]) / (Z[r] + E);
      o[r] = (__bf16)((float)r4[r] * y);
      S[r] = ew[r] * S[r] + ek * (float)v4[r];
      Z[r] = ew[r] * Z[r] + ek;
    }
    *(bf16x4*)&a2[p] = o;
  }
}

// ---------------------------------------------------------------------------
// Workspace layout (peak ~169 MB):
//   [0)    ka 16M | [16M) va | [32M) ra (=sigmoid r)
//   [48M)  a2 16M -> reused as g2buf after gemm7
//   [64M)  h8 (fp8 8M) -> reused as h28 (fp8, written by gemm7)
//   [80M)  x1h 16M
//   [96M)  kk8 (fp8, 32M)
//   [128M) scan state S/Z (4 x 2M)
//   [160M) packed weights (~0.9 MB)
// ---------------------------------------------------------------------------
extern "C" void kernel_launch(void* const* d_in, const int* in_sizes, int n_in,
                              void* d_out, int out_size, void* d_ws, size_t ws_size,
                              hipStream_t stream) {
  const float* x     = (const float*)d_in[0];
  const float* Wk    = (const float*)d_in[1];
  const float* Wv    = (const float*)d_in[2];
  const float* Wr    = (const float*)d_in[3];
  const float* Wo    = (const float*)d_in[4];
  const float* Wkf   = (const float*)d_in[5];
  const float* Wvf   = (const float*)d_in[6];
  const float* Wrf   = (const float*)d_in[7];
  const float* g1    = (const float*)d_in[8];
  const float* b1    = (const float*)d_in[9];
  const float* g2    = (const float*)d_in[10];
  const float* b2    = (const float*)d_in[11];
  const float* decay = (const float*)d_in[12];
  const float* first = (const float*)d_in[13];
  float* out = (float*)d_out;
  char* ws = (char*)d_ws;

  __bf16* ka     = (__bf16*)(ws + 0);
  __bf16* va     = (__bf16*)(ws + 16777216LL);
  __bf16* ra     = (__bf16*)(ws + 33554432LL);
  __bf16* a2     = (__bf16*)(ws + 50331648LL);
  __bf16* g2buf  = (__bf16*)(ws + 50331648LL);      // reuses a2 (dead after gemm7)
  unsigned char* h8  = (unsigned char*)(ws + 67108864LL);
  unsigned char* h28 = (unsigned char*)(ws + 67108864LL);  // reuses h8 (dead)
  __bf16* x1h    = (__bf16*)(ws + 83886080LL);
  unsigned char* kk8 = (unsigned char*)(ws + 100663296LL);
  float*  Sloc   = (float*)(ws + 134217728LL);
  float*  Zloc   = (float*)(ws + 137363456LL);
  float*  Sstart = (float*)(ws + 140509184LL);
  float*  Zstart = (float*)(ws + 143654912LL);
  __bf16* WoT    = (__bf16*)(ws + 167772160LL);
  unsigned char* Wkvr8 = (unsigned char*)(ws + 167903232LL);
  unsigned char* Wkfr8 = (unsigned char*)(ws + 168099840LL);
  unsigned char* Wvf8  = (unsigned char*)(ws + 168427520LL);

  pack_weights<<<1024, 256, 0, stream>>>(Wk, Wv, Wr, Wo, Wkf, Wvf, Wrf,
                                         WoT, Wkvr8, Wkfr8, Wvf8);

  // --- SpatialMix ---
  ln_kernel<<<NTOK / 4, 256, 0, stream>>>(x, g1, b1, h8);
  gemm9<256, 0><<<dim3(NTOK / 128, 6), 256, 0, stream>>>(
      h8, Wkvr8, NTOK, ka, nullptr, nullptr, nullptr, nullptr, nullptr);
  wkv_phase1<<<BDIM * NCHUNK / 4, 256, 0, stream>>>(ka, va, decay, Sloc, Zloc);
  wkv_phase2<<<BDIM, 256, 0, stream>>>(Sloc, Zloc, decay, Sstart, Zstart);
  wkv_phase3<<<BDIM * NCHUNK / 4, 256, 0, stream>>>(ka, va, ra, decay, first,
                                                    Sstart, Zstart, a2);
  // x1 = x + a2@Wo fused with LN2 -> x1h (bf16), h28 (fp8 permuted)
  gemm7<<<NTOK / 64, 256, 0, stream>>>(a2, WoT, x, g2, b2, x1h, h28);

  // --- ChannelMix ---
  gemm9<256, 2><<<dim3(NTOK / 128, 10), 256, 0, stream>>>(
      h28, Wkfr8, NTOK, nullptr, g2buf, kk8, nullptr, nullptr, nullptr);
  gemm9<1024, 3><<<dim3(NTOK / 128, 2), 256, 0, stream>>>(
      kk8, Wvf8, NTOK, nullptr, nullptr, nullptr, out, x1h, g2buf);
}